// Round 12
// baseline (379.792 us; speedup 1.0000x reference)
//
#include <hip/hip_runtime.h>
#include <hip/hip_fp16.h>

// GCN: 4x (gcn_conv + relu) + global mean pool + linear out.
// N=100000 nodes, E=1000000 edges, G=4096 graphs, F_IN=9, H=64.
// R1: wave-per-node gather MLP restructure; layer-4 agg fused with out-proj.
// R2 (FAILED, 237us): global bucket-cursor scatter -- atomic contention.
// R3: scatter-free CSR build (LDS chunk sort + single-writer bucket gather).
// R4: fp16 message rows.  FETCH halved, time flat => NOT byte-bound.
// R5: 8x8 subgroups + persistent waves + row_ptr prefetch: 72->63us/agg.
// R6 (FAILED): edge-centric LDS-atomic aggregation -- LDS atomics serialized.
// R7: standalone MFMA lin64 net-negative, but VALIDATED 16x16x32_f16 layouts.
// R8: lin64 deleted; transform fused into agg epilogue via MFMA.  451 -> 379us.
// R9-R11: 2-deep A/B pipeline: agg_fused 65->47 (keep); agg64_out regressed.
// R12: selective revert (agg64_out = R8 while-loop) + premul into scanC: 341us.
// R13: deg-free graph build.  The bucket sort already partitions node n's
//     edges into bucket n>>7, so per-node degree is an LDS count inside the
//     gather (pass A) -- k_deg's 1M random global atomics and the 3-kernel
//     deg scan are deleted.  Bucket bases = hoffC column sums (coalesced) +
//     one 782-wide scan.  gcount deleted too: batch is SORTED, so k_final
//     binary-searches per-graph counts.  Aggregation kernels untouched.

static inline size_t align256(size_t x){ return (x + 255) & ~size_t(255); }

#define CHUNK 2048          // edges per sort chunk

struct __align__(8)  h4v { __half2 a, b; };        // 4 halves = 8B
struct __align__(16) h8v { __half2 a, b, c, d; };  // 8 halves = 16B (agg gather)

typedef _Float16 f16x8 __attribute__((ext_vector_type(8)));
typedef float    f32x4 __attribute__((ext_vector_type(4)));

__global__ void k_zero(float* gsum, int G){
  int i = blockIdx.x*blockDim.x + threadIdx.x;
  if (i < G) gsum[i] = 0.f;
}

// pass 1: sort a 2048-edge chunk by bucket entirely in LDS, emit the sorted
// image (coalesced) + the chunk's 783-entry bucket-offset row (coalesced).
// Entry packed as (src<<7)|(dst&127); src < 2^17 fits.
__global__ __launch_bounds__(256) void k_sortchunk(
    const int* __restrict__ src, const int* __restrict__ dst,
    int* __restrict__ binned, int* __restrict__ hoffC, int E){
  __shared__ int hcnt[1024];            // 782 used; padded pow2 for scan
  __shared__ int simg[CHUNK];
  int c = blockIdx.x, t = threadIdx.x;
  int e0 = c*CHUNK;
  int cnt = E - e0; if (cnt > CHUNK) cnt = CHUNK;

  for (int i = t; i < 1024; i += 256) hcnt[i] = 0;
  __syncthreads();

  int b_[8], r_[8], v_[8];              // static-indexed (stays in VGPRs)
  #pragma unroll
  for (int j = 0; j < 8; j++){
    int i = t + j*256;
    if (i < cnt){
      int d = dst[e0+i];
      int s = src[e0+i];
      int b = d >> 7;
      b_[j] = b;
      r_[j] = atomicAdd(&hcnt[b], 1);
      v_[j] = (s << 7) | (d & 127);
    } else b_[j] = -1;
  }
  __syncthreads();

  // in-place Hillis-Steele inclusive scan of hcnt[0..1023]
  int own[4];
  #pragma unroll
  for (int j = 0; j < 4; j++) own[j] = hcnt[t + j*256];
  for (int off = 1; off < 1024; off <<= 1){
    int nv[4];
    #pragma unroll
    for (int j = 0; j < 4; j++){
      int i = t + j*256;
      nv[j] = hcnt[i] + ((i >= off) ? hcnt[i-off] : 0);
    }
    __syncthreads();
    #pragma unroll
    for (int j = 0; j < 4; j++) hcnt[t + j*256] = nv[j];
    __syncthreads();
  }
  // inclusive -> exclusive
  #pragma unroll
  for (int j = 0; j < 4; j++) hcnt[t + j*256] -= own[j];
  __syncthreads();

  // emit bucket-offset row (hcnt[782] == cnt since buckets >=782 are empty)
  for (int i = t; i < 783; i += 256) hoffC[c*783 + i] = hcnt[i];

  // place edges bucket-major in LDS
  #pragma unroll
  for (int j = 0; j < 8; j++)
    if (b_[j] >= 0) simg[hcnt[b_[j]] + r_[j]] = v_[j];
  __syncthreads();

  // coalesced stream-out of the sorted chunk image
  for (int i = t; i < cnt; i += 256) binned[e0 + i] = simg[i];
}

// bucket totals: btot[b] = sum over chunks of (hoffC[c][b+1]-hoffC[c][b]).
// Threads = buckets -> reads coalesced in b for each c.
__global__ void k_bktsum(const int* __restrict__ hoffC, int* __restrict__ btot,
                         int NC, int NBK){
  int b = blockIdx.x*blockDim.x + threadIdx.x;
  if (b >= NBK) return;
  int tot = 0;
  for (int c = 0; c < NC; c++){
    int h0 = hoffC[c*783 + b];
    int h1 = hoffC[c*783 + b + 1];
    tot += h1 - h0;
  }
  btot[b] = tot;
}

// single-block exclusive scan of bucket totals (NBK=782 <= 1024) -> bbase;
// also writes the row_ptr[N]=E sentinel.
__global__ __launch_bounds__(1024) void k_bktscan(
    const int* __restrict__ btot, int* __restrict__ bbase,
    int* __restrict__ row_ptr, int NBK, int N, int E){
  __shared__ int s[1024];
  int t = threadIdx.x;
  int v = (t < NBK) ? btot[t] : 0;
  s[t] = v; __syncthreads();
  for (int off = 1; off < 1024; off <<= 1){
    int add = (t >= off) ? s[t-off] : 0; __syncthreads();
    s[t] += add; __syncthreads();
  }
  if (t < NBK) bbase[t] = s[t] - v;
  if (t == 0) row_ptr[N] = E;
}

// pass 2 (extended): WG per bucket.
//   pass A: count per-node degrees in LDS (node n's edges all live in
//           bucket n>>7) -> deg -> 128-entry LDS scan -> row_ptr, dis, cursors
//   pass B: place edges into the bucket's own csr region (single-writer).
__global__ __launch_bounds__(256) void k_gather2(
    const int* __restrict__ binned, const int* __restrict__ hoffC,
    const int* __restrict__ bbase,
    int* __restrict__ row_ptr, float* __restrict__ dis,
    int* __restrict__ csr, int N, int NC){
  __shared__ int lcur[128];
  __shared__ int lscan[128];
  int b = blockIdx.x, t = threadIdx.x;
  int n0 = b << 7;
  int nn = N - n0; if (nn > 128) nn = 128;
  if (t < 128) lcur[t] = 0;
  __syncthreads();
  // pass A: degree count
  for (int c = t; c < NC; c += 256){
    int o0 = hoffC[c*783 + b];
    int o1 = hoffC[c*783 + b + 1];
    int base = c*CHUNK;
    for (int k = o0; k < o1; k++)
      atomicAdd(&lcur[binned[base + k] & 127], 1);
  }
  __syncthreads();
  int degv = (t < 128) ? lcur[t] : 0;
  if (t < 128) lscan[t] = degv;
  __syncthreads();
  for (int off = 1; off < 128; off <<= 1){
    int add = (t < 128 && t >= off) ? lscan[t-off] : 0;
    __syncthreads();
    if (t < 128) lscan[t] += add;
    __syncthreads();
  }
  int bb = bbase[b];
  if (t < nn){
    int row = bb + lscan[t] - degv;        // exclusive
    row_ptr[n0 + t] = row;
    dis[n0 + t] = rsqrtf((float)(degv + 1));  // +1 self-loop
    lcur[t] = row;                          // cursor for pass B
  }
  __syncthreads();
  // pass B: place
  for (int c = t; c < NC; c += 256){
    int o0 = hoffC[c*783 + b];
    int o1 = hoffC[c*783 + b + 1];
    int base = c*CHUNK;
    for (int k = o0; k < o1; k++){
      int v = binned[base + k];
      int pos = atomicAdd(&lcur[v & 127], 1);
      csr[pos] = v >> 7;
    }
  }
}

// xs[n] = x[n] * dis[n]  (premultiply so the gather loop has one load per edge)
__global__ void k_premul(const float* __restrict__ x, const float* __restrict__ dis,
                         float* __restrict__ xs, int N){
  int i = blockIdx.x*blockDim.x + threadIdx.x;
  if (i < N*9) xs[i] = x[i]*dis[i/9];
}

// layer-1 aggregation over xs (9 features): thread per (node, feature), unroll-4 MLP
__global__ void k_agg9(const float* __restrict__ xs, const float* __restrict__ dis,
                       const int* __restrict__ row_ptr, const int* __restrict__ csr,
                       float* __restrict__ xagg, int N){
  int tid = blockIdx.x*blockDim.x + threadIdx.x;
  if (tid >= N*9) return;
  int n = tid/9, f = tid - n*9;
  float dn = dis[n];
  int s0 = row_ptr[n], s1 = row_ptr[n+1];
  float a0 = xs[tid];                 // self-loop term (x[n]*dis[n])
  float a1 = 0.f, a2 = 0.f, a3 = 0.f;
  int j = s0;
  for (; j + 3 < s1; j += 4){
    int e0 = csr[j], e1 = csr[j+1], e2 = csr[j+2], e3 = csr[j+3];
    a0 += xs[e0*9+f];
    a1 += xs[e1*9+f];
    a2 += xs[e2*9+f];
    a3 += xs[e3*9+f];
  }
  for (; j < s1; j++) a0 += xs[csr[j]*9+f];
  xagg[tid] = ((a0+a1)+(a2+a3))*dn;
}

// MFMA epilogue shared by the fused kernels.  hlw = this wave's 16x72-half
// LDS tile (row i = node wid + i*nwaves, cols 0..63 = dis*h fp16, 64..71 pad).
// Computes m' = (dis*h) @ Wn via D = A.B with A = Wn^T frags, B = h^T:
//   A[i][k]: lane(lm,lk) reg j -> Wn[(kb*32+lk*8+j)*64 + ft*16 + lm]
//   B[k][c]: lane(lm,lk) reg j -> hl[c=lm][kb*32+lk*8+j]  (ds_read_b128)
//   D[i][c]: lane(lm,lk) reg j -> m'[node lm][ft*16 + lk*4 + j]  (8B store)
__device__ __forceinline__ void mfma_epilogue(
    const _Float16* hlw, const f16x8 (&wf)[4][2],
    __half* __restrict__ mo, int wid, int nwaves, int N, int lane){
  int lm = lane & 15, lk = lane >> 4;
  f16x8 hb0 = *(const f16x8*)(hlw + lm*72 + lk*8);
  f16x8 hb1 = *(const f16x8*)(hlw + lm*72 + 32 + lk*8);
  int node = wid + lm*nwaves;
  bool ok = (node < N);
  __half* row = mo + (size_t)node*64;
  #pragma unroll
  for (int ft = 0; ft < 4; ft++){
    f32x4 acc = {0.f, 0.f, 0.f, 0.f};
    acc = __builtin_amdgcn_mfma_f32_16x16x32_f16(wf[ft][0], hb0, acc, 0, 0, 0);
    acc = __builtin_amdgcn_mfma_f32_16x16x32_f16(wf[ft][1], hb1, acc, 0, 0, 0);
    if (ok){
      h4v o;
      o.a = __floats2half2_rn(acc[0], acc[1]);
      o.b = __floats2half2_rn(acc[2], acc[3]);
      *(h4v*)(row + ft*16 + lk*4) = o;
    }
  }
}

#define LOAD_WFRAGS(Wn)                                                    \
  f16x8 wf[4][2];                                                          \
  { int lm_ = lane & 15, lk_ = lane >> 4;                                  \
    _Pragma("unroll") for (int ft = 0; ft < 4; ft++)                       \
    _Pragma("unroll") for (int kb = 0; kb < 2; kb++)                       \
    _Pragma("unroll") for (int j = 0; j < 8; j++)                          \
      wf[ft][kb][j] = (_Float16)Wn[(kb*32 + lk_*8 + j)*64 + ft*16 + lm_]; }

// layer 1 transform fused with next-layer message build:
// h1 = relu(xagg@W1+b1); m2 = fp16((dis*h1) @ W2).  h1 never stored.
__global__ __launch_bounds__(256) void k_lin1_fused(
    const float* __restrict__ xagg, const float* __restrict__ W1,
    const float* __restrict__ b1, const float* __restrict__ dis,
    const float* __restrict__ W2, __half* __restrict__ mo, int N, int nwaves){
  __shared__ float W1l[576];
  __shared__ float b1l[64];
  __shared__ _Float16 hl[4][16*72];
  int t = threadIdx.x;
  for (int i = t; i < 576; i += 256) W1l[i] = W1[i];
  if (t < 64) b1l[t] = b1[t];
  __syncthreads();
  int lane = t & 63, w = t >> 6;
  int wid = (blockIdx.x*blockDim.x + t) >> 6;
  LOAD_WFRAGS(W2)
  _Float16* hlw = hl[w];
  for (int i = 0; i < 16; i++){
    int n = wid + i*nwaves;
    _Float16 hv = (_Float16)0.f;
    if (n < N){
      float acc = b1l[lane];
      #pragma unroll
      for (int k = 0; k < 9; k++) acc = fmaf(xagg[n*9+k], W1l[k*64+lane], acc);
      hv = (_Float16)(fmaxf(acc, 0.f) * dis[n]);
    }
    hlw[i*72 + lane] = hv;
  }
  mfma_epilogue(hlw, wf, mo, wid, nwaves, N, lane);
}

// NOTE: param is g_ (NOT `a`): body reads members .a/.b/.c/.d and the
// preprocessor would substitute a same-named parameter into member tokens.
#define ACC8(g_)  do{ float2 t_;                                   \
  t_ = __half22float2((g_).a); acc0 += t_.x; acc1 += t_.y;         \
  t_ = __half22float2((g_).b); acc2 += t_.x; acc3 += t_.y;         \
  t_ = __half22float2((g_).c); acc4 += t_.x; acc5 += t_.y;         \
  t_ = __half22float2((g_).d); acc6 += t_.x; acc7 += t_.y; }while(0)

#define RED3(v)  do{ v += __shfl_xor(v, 8,64);                     \
                     v += __shfl_xor(v,16,64);                     \
                     v += __shfl_xor(v,32,64); }while(0)

// --- pipeline stages (named register sets; no runtime-indexed arrays) ---
// ISSUE: prefetch row_ptr 2 ahead, load self row + dis, csr indices, and
// launch the node's 16 gathers.  REDUCE (next half-step) consumes them.
#define AGG_ISSUE(n_, rp0_, rp1_, rn0_, rn1_, e0_, e1_, g0_, g1_, sf_, dn_) \
  do{                                                                      \
    int nn_ = (n_) + 2*nwaves;                                             \
    rn0_ = 0; rn1_ = 0;                                                    \
    if (nn_ < N){ rn0_ = row_ptr[nn_]; rn1_ = row_ptr[nn_+1]; }            \
    e0_ = -1; e1_ = -1;                                                    \
    if ((n_) < N){                                                         \
      sf_ = m[(size_t)(n_)*8 + q2];                                        \
      dn_ = dis[n_];                                                       \
      int j0_ = (rp0_) + sub, j1_ = (rp0_) + 8 + sub;                      \
      if (j0_ < (rp1_)) e0_ = csr[j0_];                                    \
      if (j1_ < (rp1_)) e1_ = csr[j1_];                                    \
      if (e0_ >= 0) g0_ = m[(size_t)e0_*8 + q2];                           \
      if (e1_ >= 0) g1_ = m[(size_t)e1_*8 + q2];                           \
    }                                                                      \
  }while(0)

#define AGG_ACCRED(n_, rp0_, rp1_, e0_, e1_, g0_, g1_, sf_, dn_)           \
      float acc0=0.f,acc1=0.f,acc2=0.f,acc3=0.f;                           \
      float acc4=0.f,acc5=0.f,acc6=0.f,acc7=0.f;                           \
      if (e0_ >= 0) ACC8(g0_);                                             \
      if (e1_ >= 0) ACC8(g1_);                                             \
      for (int j_ = (rp0_) + 16 + sub; j_ < (rp1_); j_ += 8){              \
        h8v gx_ = m[(size_t)csr[j_]*8 + q2]; ACC8(gx_);                    \
      }                                                                    \
      RED3(acc0); RED3(acc1); RED3(acc2); RED3(acc3);                      \
      RED3(acc4); RED3(acc5); RED3(acc6); RED3(acc7);                      \
      float2 s01=__half22float2((sf_).a), s23=__half22float2((sf_).b);     \
      float2 s45=__half22float2((sf_).c), s67=__half22float2((sf_).d);     \
      float r0 = fmaxf(fmaf(acc0 + s01.x, dn_, bb0.x), 0.f);               \
      float r1 = fmaxf(fmaf(acc1 + s01.y, dn_, bb0.y), 0.f);               \
      float r2 = fmaxf(fmaf(acc2 + s23.x, dn_, bb0.z), 0.f);               \
      float r3 = fmaxf(fmaf(acc3 + s23.y, dn_, bb0.w), 0.f);               \
      float r4 = fmaxf(fmaf(acc4 + s45.x, dn_, bb1.x), 0.f);               \
      float r5 = fmaxf(fmaf(acc5 + s45.y, dn_, bb1.y), 0.f);               \
      float r6 = fmaxf(fmaf(acc6 + s67.x, dn_, bb1.z), 0.f);               \
      float r7 = fmaxf(fmaf(acc7 + s67.y, dn_, bb1.w), 0.f);

// REDUCE for the fused kernels: writes fp16(dn*h) into the wave's LDS tile
#define AGG_REDUCE(n_, rp0_, rp1_, e0_, e1_, g0_, g1_, sf_, dn_, i_)       \
  do{                                                                      \
    if ((n_) < N){                                                         \
      AGG_ACCRED(n_, rp0_, rp1_, e0_, e1_, g0_, g1_, sf_, dn_)             \
      if (sub == 0){                                                       \
        h8v hv_;                                                           \
        hv_.a = __floats2half2_rn(r0*(dn_), r1*(dn_));                     \
        hv_.b = __floats2half2_rn(r2*(dn_), r3*(dn_));                     \
        hv_.c = __floats2half2_rn(r4*(dn_), r5*(dn_));                     \
        hv_.d = __floats2half2_rn(r6*(dn_), r7*(dn_));                     \
        *(h8v*)(hlw + (i_)*72 + q2*8) = hv_;                               \
      }                                                                    \
    } else if (sub == 0){                                                  \
      h8v z_; z_.a = __floats2half2_rn(0.f, 0.f);                          \
      z_.b = z_.a; z_.c = z_.a; z_.d = z_.a;                               \
      *(h8v*)(hlw + (i_)*72 + q2*8) = z_;                                  \
    }                                                                      \
  }while(0)

// layers 2,3: pipelined gather + fused next-layer transform.
__global__ __launch_bounds__(256) void k_agg_fused(
    const h8v* __restrict__ m, const float* __restrict__ dis,
    const float* __restrict__ b, const float* __restrict__ Wn,
    const int* __restrict__ row_ptr, const int* __restrict__ csr,
    __half* __restrict__ mo, int N, int nwaves){
  __shared__ _Float16 hl[4][16*72];
  int t = threadIdx.x;
  int lane = t & 63, w = t >> 6;
  int sub = lane >> 3, q2 = lane & 7;
  int wid = (blockIdx.x*blockDim.x + t) >> 6;
  _Float16* hlw = hl[w];
  const float4* b4 = (const float4*)b;
  float4 bb0 = b4[q2*2], bb1 = b4[q2*2+1];

  int nA = wid,          rA0 = 0, rA1 = 0;
  int nB = wid + nwaves, rB0 = 0, rB1 = 0;
  if (nA < N){ rA0 = row_ptr[nA]; rA1 = row_ptr[nA+1]; }
  if (nB < N){ rB0 = row_ptr[nB]; rB1 = row_ptr[nB+1]; }
  int eA0, eA1, eB0, eB1, rnA0, rnA1, rnB0, rnB1;
  h8v gA0, gA1, sfA, gB0, gB1, sfB;
  float dnA = 0.f, dnB = 0.f;
  AGG_ISSUE(nA, rA0, rA1, rnA0, rnA1, eA0, eA1, gA0, gA1, sfA, dnA);
  for (int p = 0; p < 8; p++){
    AGG_ISSUE(nB, rB0, rB1, rnB0, rnB1, eB0, eB1, gB0, gB1, sfB, dnB);
    AGG_REDUCE(nA, rA0, rA1, eA0, eA1, gA0, gA1, sfA, dnA, 2*p);
    nA += 2*nwaves; rA0 = rnA0; rA1 = rnA1;
    if (p < 7)
      AGG_ISSUE(nA, rA0, rA1, rnA0, rnA1, eA0, eA1, gA0, gA1, sfA, dnA);
    AGG_REDUCE(nB, rB0, rB1, eB0, eB1, gB0, gB1, sfB, dnB, 2*p+1);
    nB += 2*nwaves; rB0 = rnB0; rB1 = rnB1;
  }
  LOAD_WFRAGS(Wn)            // loaded at epilogue: not live during main loop
  mfma_epilogue(hlw, wf, mo, wid, nwaves, N, lane);
}

// layer 4 (R8's measured-60us while-loop form): aggregation fused with output
// projection: per-node dot(h4, Wout) -> wave reduce -> atomic segment add.
__global__ __launch_bounds__(256) void k_agg64_out(
    const h8v* __restrict__ m, const float* __restrict__ dis,
    const float* __restrict__ b, const float* __restrict__ Wout,
    const int* __restrict__ batch,
    const int* __restrict__ row_ptr, const int* __restrict__ csr,
    float* gsum, int N, int nwaves){
  int lane = threadIdx.x & 63;
  int sub = lane >> 3, q2 = lane & 7;
  int n = (blockIdx.x*blockDim.x + threadIdx.x) >> 6;
  if (n >= N) return;
  int rp0 = row_ptr[n], rp1 = row_ptr[n+1];
  const float4* b4 = (const float4*)b;
  const float4* wo4 = (const float4*)Wout;
  while (true){
    int nn = n + nwaves;
    int np0 = 0, np1 = 0;
    if (nn < N){ np0 = row_ptr[nn]; np1 = row_ptr[nn+1]; }   // prefetch (indep)
    h8v sf = m[(size_t)n*8 + q2];                            // self row (indep)
    float dn = dis[n];
    int bg = batch[n];
    float acc0=0.f,acc1=0.f,acc2=0.f,acc3=0.f,acc4=0.f,acc5=0.f,acc6=0.f,acc7=0.f;
    int s1 = rp1;
    int j0 = rp0 + sub, j1 = rp0 + 8 + sub;
    if (j0 < s1){ h8v a = m[(size_t)csr[j0]*8 + q2]; ACC8(a); }
    if (j1 < s1){ h8v a = m[(size_t)csr[j1]*8 + q2]; ACC8(a); }
    for (int j = rp0 + 16 + sub; j < s1; j += 8){            // rare (deg>16)
      h8v a = m[(size_t)csr[j]*8 + q2]; ACC8(a);
    }
    RED3(acc0); RED3(acc1); RED3(acc2); RED3(acc3);
    RED3(acc4); RED3(acc5); RED3(acc6); RED3(acc7);
    float2 s01 = __half22float2(sf.a), s23 = __half22float2(sf.b);
    float2 s45 = __half22float2(sf.c), s67 = __half22float2(sf.d);
    float4 bb0 = b4[q2*2], bb1 = b4[q2*2+1];
    float4 w0 = wo4[q2*2], w1 = wo4[q2*2+1];
    float r0 = fmaxf(fmaf(acc0 + s01.x, dn, bb0.x), 0.f);
    float r1 = fmaxf(fmaf(acc1 + s01.y, dn, bb0.y), 0.f);
    float r2 = fmaxf(fmaf(acc2 + s23.x, dn, bb0.z), 0.f);
    float r3 = fmaxf(fmaf(acc3 + s23.y, dn, bb0.w), 0.f);
    float r4 = fmaxf(fmaf(acc4 + s45.x, dn, bb1.x), 0.f);
    float r5 = fmaxf(fmaf(acc5 + s45.y, dn, bb1.y), 0.f);
    float r6 = fmaxf(fmaf(acc6 + s67.x, dn, bb1.z), 0.f);
    float r7 = fmaxf(fmaf(acc7 + s67.y, dn, bb1.w), 0.f);
    float p = r0*w0.x + r1*w0.y + r2*w0.z + r3*w0.w
            + r4*w1.x + r5*w1.y + r6*w1.z + r7*w1.w;
    p += __shfl_xor(p,1,64); p += __shfl_xor(p,2,64); p += __shfl_xor(p,4,64);
    if (lane == 0) atomicAdd(&gsum[bg], p);
    if (nn >= N) break;
    n = nn; rp0 = np0; rp1 = np1;
  }
}

// final: per-graph count via binary search on SORTED batch (no atomics),
// then mean + bias.
__global__ void k_final(const float* __restrict__ gsum, const int* __restrict__ batch,
                        const float* __restrict__ bout, float* __restrict__ out,
                        int G, int N){
  int g = blockIdx.x*blockDim.x + threadIdx.x;
  if (g >= G) return;
  int lo = 0, hi = N;
  while (lo < hi){ int mid = (lo+hi)>>1; if (batch[mid] <  g) lo = mid+1; else hi = mid; }
  int lb = lo;
  lo = 0; hi = N;
  while (lo < hi){ int mid = (lo+hi)>>1; if (batch[mid] <= g) lo = mid+1; else hi = mid; }
  int c = lo - lb;
  out[g] = gsum[g]/(float)(c > 0 ? c : 1) + bout[0];
}

extern "C" void kernel_launch(void* const* d_in, const int* in_sizes, int n_in,
                              void* d_out, int out_size, void* d_ws, size_t ws_size,
                              hipStream_t stream){
  const float* x    = (const float*)d_in[0];
  const int*   ei   = (const int*)d_in[1];
  const int*   batch= (const int*)d_in[2];
  const float* W1 = (const float*)d_in[3];  const float* b1 = (const float*)d_in[4];
  const float* W2 = (const float*)d_in[5];  const float* b2 = (const float*)d_in[6];
  const float* W3 = (const float*)d_in[7];  const float* b3 = (const float*)d_in[8];
  const float* W4 = (const float*)d_in[9];  const float* b4 = (const float*)d_in[10];
  const float* Wout = (const float*)d_in[11]; const float* bout = (const float*)d_in[12];
  float* out = (float*)d_out;

  const int N = in_sizes[0]/9;
  const int E = in_sizes[1]/2;
  const int G = out_size;
  const int* src = ei;        // edge_index[0]
  const int* dst = ei + E;    // edge_index[1]

  char* ws = (char*)d_ws;
  size_t off = 0;
  auto alloc = [&](size_t bytes){ void* p = ws + off; off = align256(off + bytes); return p; };
  int*   row_ptr  = (int*)  alloc((size_t)(N+1)*4);
  int*   csr      = (int*)  alloc((size_t)E*4);
  float* dis      = (float*)alloc((size_t)N*4);
  const int NBK = (N + 127)/128;        // 782 buckets of 128 dst nodes
  const int NC  = (E + CHUNK-1)/CHUNK;  // 489 sort chunks
  int*   hoffC    = (int*)  alloc((size_t)NC*783*4);   // per-chunk bucket offsets
  int*   btot     = (int*)  alloc((size_t)NBK*4);
  int*   bbase    = (int*)  alloc((size_t)NBK*4);
  float* gsum     = (float*)alloc((size_t)G*4);
  __half* mA      = (__half*)alloc((size_t)N*64*2);  // fp16 message ping
  __half* mB      = (__half*)alloc((size_t)N*64*2);  // fp16 message pong
  // aliases (lifetimes verified):
  int*   binned   = (int*)mA;              // 4MB <= 12.8MB; dead after k_gather2
  float* xs       = (float*)mB;            // 3.6MB; dead after k_agg9
  float* xagg     = xs + (size_t)N*9;      // 3.6MB; dead after k_lin1_fused
  // m2 = mA (written by lin1_fused, after binned dead)
  // m3 = mB (written by aggF layer2, after xs/xagg dead)
  // m4 = mA (written by aggF layer3, after m2 dead)

  const int AGG_BLOCKS = 2048;             // persistent: 8 blocks/CU on 256 CUs
  const int AGG_WAVES  = AGG_BLOCKS*4;     // 8192 waves; 16*8192 >= N (batch=16)

  k_zero     <<<(G+255)/256, 256, 0, stream>>>(gsum, G);
  k_sortchunk<<<NC, 256, 0, stream>>>(src, dst, binned, hoffC, E);
  k_bktsum   <<<(NBK+255)/256, 256, 0, stream>>>(hoffC, btot, NC, NBK);
  k_bktscan  <<<1, 1024, 0, stream>>>(btot, bbase, row_ptr, NBK, N, E);
  k_gather2  <<<NBK, 256, 0, stream>>>(binned, hoffC, bbase, row_ptr, dis, csr, N, NC);

  // layer 1: premultiply, aggregate (9 feats), transform fused with m2 build
  k_premul<<<(N*9+255)/256, 256, 0, stream>>>(x, dis, xs, N);
  k_agg9  <<<(N*9+255)/256, 256, 0, stream>>>(xs, dis, row_ptr, csr, xagg, N);
  k_lin1_fused<<<AGG_BLOCKS, 256, 0, stream>>>(xagg, W1, b1, dis, W2, mA, N, AGG_WAVES);

  // layer 2: aggregate m2 -> h2 (regs) -> m3   (uses b2, W3)
  k_agg_fused<<<AGG_BLOCKS, 256, 0, stream>>>((const h8v*)mA, dis, b2, W3,
                                              row_ptr, csr, mB, N, AGG_WAVES);
  // layer 3: aggregate m3 -> h3 (regs) -> m4   (uses b3, W4)
  k_agg_fused<<<AGG_BLOCKS, 256, 0, stream>>>((const h8v*)mB, dis, b3, W4,
                                              row_ptr, csr, mA, N, AGG_WAVES);
  // layer 4: aggregate m4 -> h4 (regs) -> Wout dot -> pooled sums
  k_agg64_out<<<AGG_BLOCKS, 256, 0, stream>>>((const h8v*)mA, dis, b4, Wout, batch,
                                              row_ptr, csr, gsum, N, AGG_WAVES);

  k_final<<<(G+255)/256, 256, 0, stream>>>(gsum, batch, bout, out, G, N);
}

// Round 13
// 308.185 us; speedup vs baseline: 1.2324x; 1.2324x over previous
//
#include <hip/hip_runtime.h>
#include <hip/hip_fp16.h>

// GCN: 4x (gcn_conv + relu) + global mean pool + linear out.
// N=100000 nodes, E=1000000 edges, G=4096 graphs, F_IN=9, H=64.
// R1: wave-per-node gather MLP restructure; layer-4 agg fused with out-proj.
// R2 (FAILED, 237us): global bucket-cursor scatter -- atomic contention.
// R3: scatter-free CSR build (LDS chunk sort + single-writer bucket gather).
// R4: fp16 message rows.  FETCH halved, time flat => NOT byte-bound.
// R5: 8x8 subgroups + persistent waves + row_ptr prefetch: 72->63us/agg.
// R6 (FAILED): edge-centric LDS-atomic aggregation -- LDS atomics serialized.
// R7: standalone MFMA lin64 net-negative, but VALIDATED 16x16x32_f16 layouts.
// R8: lin64 deleted; transform fused into agg epilogue via MFMA.  451 -> 379us.
// R9-R11: 2-deep A/B pipeline: agg_fused 65->47 (keep); agg64_out regressed.
// R12: selective revert + premul-into-scanC: 341us.
// R13: deg-free graph build (bucket sort implies degrees; k_deg + 3 scan
//     kernels deleted; k_final binary-searches sorted batch).  Mechanism
//     worked (-36us elsewhere) BUT k_bktsum was launched with 782 threads
//     TOTAL (4 blocks, 0.14% occupancy) -> 74.8us serial-latency disaster.
// R14: k_bktsum reshaped to one block PER bucket (256 threads stride the
//     chunks, LDS tree-reduce).  Same arithmetic, ~1000x more parallelism.

static inline size_t align256(size_t x){ return (x + 255) & ~size_t(255); }

#define CHUNK 2048          // edges per sort chunk

struct __align__(8)  h4v { __half2 a, b; };        // 4 halves = 8B
struct __align__(16) h8v { __half2 a, b, c, d; };  // 8 halves = 16B (agg gather)

typedef _Float16 f16x8 __attribute__((ext_vector_type(8)));
typedef float    f32x4 __attribute__((ext_vector_type(4)));

__global__ void k_zero(float* gsum, int G){
  int i = blockIdx.x*blockDim.x + threadIdx.x;
  if (i < G) gsum[i] = 0.f;
}

// pass 1: sort a 2048-edge chunk by bucket entirely in LDS, emit the sorted
// image (coalesced) + the chunk's 783-entry bucket-offset row (coalesced).
// Entry packed as (src<<7)|(dst&127); src < 2^17 fits.
__global__ __launch_bounds__(256) void k_sortchunk(
    const int* __restrict__ src, const int* __restrict__ dst,
    int* __restrict__ binned, int* __restrict__ hoffC, int E){
  __shared__ int hcnt[1024];            // 782 used; padded pow2 for scan
  __shared__ int simg[CHUNK];
  int c = blockIdx.x, t = threadIdx.x;
  int e0 = c*CHUNK;
  int cnt = E - e0; if (cnt > CHUNK) cnt = CHUNK;

  for (int i = t; i < 1024; i += 256) hcnt[i] = 0;
  __syncthreads();

  int b_[8], r_[8], v_[8];              // static-indexed (stays in VGPRs)
  #pragma unroll
  for (int j = 0; j < 8; j++){
    int i = t + j*256;
    if (i < cnt){
      int d = dst[e0+i];
      int s = src[e0+i];
      int b = d >> 7;
      b_[j] = b;
      r_[j] = atomicAdd(&hcnt[b], 1);
      v_[j] = (s << 7) | (d & 127);
    } else b_[j] = -1;
  }
  __syncthreads();

  // in-place Hillis-Steele inclusive scan of hcnt[0..1023]
  int own[4];
  #pragma unroll
  for (int j = 0; j < 4; j++) own[j] = hcnt[t + j*256];
  for (int off = 1; off < 1024; off <<= 1){
    int nv[4];
    #pragma unroll
    for (int j = 0; j < 4; j++){
      int i = t + j*256;
      nv[j] = hcnt[i] + ((i >= off) ? hcnt[i-off] : 0);
    }
    __syncthreads();
    #pragma unroll
    for (int j = 0; j < 4; j++) hcnt[t + j*256] = nv[j];
    __syncthreads();
  }
  // inclusive -> exclusive
  #pragma unroll
  for (int j = 0; j < 4; j++) hcnt[t + j*256] -= own[j];
  __syncthreads();

  // emit bucket-offset row (hcnt[782] == cnt since buckets >=782 are empty)
  for (int i = t; i < 783; i += 256) hoffC[c*783 + i] = hcnt[i];

  // place edges bucket-major in LDS
  #pragma unroll
  for (int j = 0; j < 8; j++)
    if (b_[j] >= 0) simg[hcnt[b_[j]] + r_[j]] = v_[j];
  __syncthreads();

  // coalesced stream-out of the sorted chunk image
  for (int i = t; i < cnt; i += 256) binned[e0 + i] = simg[i];
}

// bucket totals: one block PER bucket; 256 threads stride the chunks and
// tree-reduce in LDS.  (R13 launched 782 threads total -> 74.8us at 0.14%
// occupancy; same arithmetic at proper parallelism is ~5us.)
__global__ __launch_bounds__(256) void k_bktsum(
    const int* __restrict__ hoffC, int* __restrict__ btot, int NC, int NBK){
  __shared__ int s[256];
  int b = blockIdx.x, t = threadIdx.x;
  int tot = 0;
  for (int c = t; c < NC; c += 256)
    tot += hoffC[c*783 + b + 1] - hoffC[c*783 + b];
  s[t] = tot; __syncthreads();
  for (int off = 128; off > 0; off >>= 1){
    if (t < off) s[t] += s[t+off];
    __syncthreads();
  }
  if (t == 0) btot[b] = s[0];
}

// single-block exclusive scan of bucket totals (NBK=782 <= 1024) -> bbase;
// also writes the row_ptr[N]=E sentinel.
__global__ __launch_bounds__(1024) void k_bktscan(
    const int* __restrict__ btot, int* __restrict__ bbase,
    int* __restrict__ row_ptr, int NBK, int N, int E){
  __shared__ int s[1024];
  int t = threadIdx.x;
  int v = (t < NBK) ? btot[t] : 0;
  s[t] = v; __syncthreads();
  for (int off = 1; off < 1024; off <<= 1){
    int add = (t >= off) ? s[t-off] : 0; __syncthreads();
    s[t] += add; __syncthreads();
  }
  if (t < NBK) bbase[t] = s[t] - v;
  if (t == 0) row_ptr[N] = E;
}

// pass 2 (extended): WG per bucket.
//   pass A: count per-node degrees in LDS (node n's edges all live in
//           bucket n>>7) -> deg -> 128-entry LDS scan -> row_ptr, dis, cursors
//   pass B: place edges into the bucket's own csr region (single-writer).
__global__ __launch_bounds__(256) void k_gather2(
    const int* __restrict__ binned, const int* __restrict__ hoffC,
    const int* __restrict__ bbase,
    int* __restrict__ row_ptr, float* __restrict__ dis,
    int* __restrict__ csr, int N, int NC){
  __shared__ int lcur[128];
  __shared__ int lscan[128];
  int b = blockIdx.x, t = threadIdx.x;
  int n0 = b << 7;
  int nn = N - n0; if (nn > 128) nn = 128;
  if (t < 128) lcur[t] = 0;
  __syncthreads();
  // pass A: degree count
  for (int c = t; c < NC; c += 256){
    int o0 = hoffC[c*783 + b];
    int o1 = hoffC[c*783 + b + 1];
    int base = c*CHUNK;
    for (int k = o0; k < o1; k++)
      atomicAdd(&lcur[binned[base + k] & 127], 1);
  }
  __syncthreads();
  int degv = (t < 128) ? lcur[t] : 0;
  if (t < 128) lscan[t] = degv;
  __syncthreads();
  for (int off = 1; off < 128; off <<= 1){
    int add = (t < 128 && t >= off) ? lscan[t-off] : 0;
    __syncthreads();
    if (t < 128) lscan[t] += add;
    __syncthreads();
  }
  int bb = bbase[b];
  if (t < nn){
    int row = bb + lscan[t] - degv;        // exclusive
    row_ptr[n0 + t] = row;
    dis[n0 + t] = rsqrtf((float)(degv + 1));  // +1 self-loop
    lcur[t] = row;                          // cursor for pass B
  }
  __syncthreads();
  // pass B: place
  for (int c = t; c < NC; c += 256){
    int o0 = hoffC[c*783 + b];
    int o1 = hoffC[c*783 + b + 1];
    int base = c*CHUNK;
    for (int k = o0; k < o1; k++){
      int v = binned[base + k];
      int pos = atomicAdd(&lcur[v & 127], 1);
      csr[pos] = v >> 7;
    }
  }
}

// xs[n] = x[n] * dis[n]  (premultiply so the gather loop has one load per edge)
__global__ void k_premul(const float* __restrict__ x, const float* __restrict__ dis,
                         float* __restrict__ xs, int N){
  int i = blockIdx.x*blockDim.x + threadIdx.x;
  if (i < N*9) xs[i] = x[i]*dis[i/9];
}

// layer-1 aggregation over xs (9 features): thread per (node, feature), unroll-4 MLP
__global__ void k_agg9(const float* __restrict__ xs, const float* __restrict__ dis,
                       const int* __restrict__ row_ptr, const int* __restrict__ csr,
                       float* __restrict__ xagg, int N){
  int tid = blockIdx.x*blockDim.x + threadIdx.x;
  if (tid >= N*9) return;
  int n = tid/9, f = tid - n*9;
  float dn = dis[n];
  int s0 = row_ptr[n], s1 = row_ptr[n+1];
  float a0 = xs[tid];                 // self-loop term (x[n]*dis[n])
  float a1 = 0.f, a2 = 0.f, a3 = 0.f;
  int j = s0;
  for (; j + 3 < s1; j += 4){
    int e0 = csr[j], e1 = csr[j+1], e2 = csr[j+2], e3 = csr[j+3];
    a0 += xs[e0*9+f];
    a1 += xs[e1*9+f];
    a2 += xs[e2*9+f];
    a3 += xs[e3*9+f];
  }
  for (; j < s1; j++) a0 += xs[csr[j]*9+f];
  xagg[tid] = ((a0+a1)+(a2+a3))*dn;
}

// MFMA epilogue shared by the fused kernels.  hlw = this wave's 16x72-half
// LDS tile (row i = node wid + i*nwaves, cols 0..63 = dis*h fp16, 64..71 pad).
// Computes m' = (dis*h) @ Wn via D = A.B with A = Wn^T frags, B = h^T:
//   A[i][k]: lane(lm,lk) reg j -> Wn[(kb*32+lk*8+j)*64 + ft*16 + lm]
//   B[k][c]: lane(lm,lk) reg j -> hl[c=lm][kb*32+lk*8+j]  (ds_read_b128)
//   D[i][c]: lane(lm,lk) reg j -> m'[node lm][ft*16 + lk*4 + j]  (8B store)
__device__ __forceinline__ void mfma_epilogue(
    const _Float16* hlw, const f16x8 (&wf)[4][2],
    __half* __restrict__ mo, int wid, int nwaves, int N, int lane){
  int lm = lane & 15, lk = lane >> 4;
  f16x8 hb0 = *(const f16x8*)(hlw + lm*72 + lk*8);
  f16x8 hb1 = *(const f16x8*)(hlw + lm*72 + 32 + lk*8);
  int node = wid + lm*nwaves;
  bool ok = (node < N);
  __half* row = mo + (size_t)node*64;
  #pragma unroll
  for (int ft = 0; ft < 4; ft++){
    f32x4 acc = {0.f, 0.f, 0.f, 0.f};
    acc = __builtin_amdgcn_mfma_f32_16x16x32_f16(wf[ft][0], hb0, acc, 0, 0, 0);
    acc = __builtin_amdgcn_mfma_f32_16x16x32_f16(wf[ft][1], hb1, acc, 0, 0, 0);
    if (ok){
      h4v o;
      o.a = __floats2half2_rn(acc[0], acc[1]);
      o.b = __floats2half2_rn(acc[2], acc[3]);
      *(h4v*)(row + ft*16 + lk*4) = o;
    }
  }
}

#define LOAD_WFRAGS(Wn)                                                    \
  f16x8 wf[4][2];                                                          \
  { int lm_ = lane & 15, lk_ = lane >> 4;                                  \
    _Pragma("unroll") for (int ft = 0; ft < 4; ft++)                       \
    _Pragma("unroll") for (int kb = 0; kb < 2; kb++)                       \
    _Pragma("unroll") for (int j = 0; j < 8; j++)                          \
      wf[ft][kb][j] = (_Float16)Wn[(kb*32 + lk_*8 + j)*64 + ft*16 + lm_]; }

// layer 1 transform fused with next-layer message build:
// h1 = relu(xagg@W1+b1); m2 = fp16((dis*h1) @ W2).  h1 never stored.
__global__ __launch_bounds__(256) void k_lin1_fused(
    const float* __restrict__ xagg, const float* __restrict__ W1,
    const float* __restrict__ b1, const float* __restrict__ dis,
    const float* __restrict__ W2, __half* __restrict__ mo, int N, int nwaves){
  __shared__ float W1l[576];
  __shared__ float b1l[64];
  __shared__ _Float16 hl[4][16*72];
  int t = threadIdx.x;
  for (int i = t; i < 576; i += 256) W1l[i] = W1[i];
  if (t < 64) b1l[t] = b1[t];
  __syncthreads();
  int lane = t & 63, w = t >> 6;
  int wid = (blockIdx.x*blockDim.x + t) >> 6;
  LOAD_WFRAGS(W2)
  _Float16* hlw = hl[w];
  for (int i = 0; i < 16; i++){
    int n = wid + i*nwaves;
    _Float16 hv = (_Float16)0.f;
    if (n < N){
      float acc = b1l[lane];
      #pragma unroll
      for (int k = 0; k < 9; k++) acc = fmaf(xagg[n*9+k], W1l[k*64+lane], acc);
      hv = (_Float16)(fmaxf(acc, 0.f) * dis[n]);
    }
    hlw[i*72 + lane] = hv;
  }
  mfma_epilogue(hlw, wf, mo, wid, nwaves, N, lane);
}

// NOTE: param is g_ (NOT `a`): body reads members .a/.b/.c/.d and the
// preprocessor would substitute a same-named parameter into member tokens.
#define ACC8(g_)  do{ float2 t_;                                   \
  t_ = __half22float2((g_).a); acc0 += t_.x; acc1 += t_.y;         \
  t_ = __half22float2((g_).b); acc2 += t_.x; acc3 += t_.y;         \
  t_ = __half22float2((g_).c); acc4 += t_.x; acc5 += t_.y;         \
  t_ = __half22float2((g_).d); acc6 += t_.x; acc7 += t_.y; }while(0)

#define RED3(v)  do{ v += __shfl_xor(v, 8,64);                     \
                     v += __shfl_xor(v,16,64);                     \
                     v += __shfl_xor(v,32,64); }while(0)

// --- pipeline stages (named register sets; no runtime-indexed arrays) ---
// ISSUE: prefetch row_ptr 2 ahead, load self row + dis, csr indices, and
// launch the node's 16 gathers.  REDUCE (next half-step) consumes them.
#define AGG_ISSUE(n_, rp0_, rp1_, rn0_, rn1_, e0_, e1_, g0_, g1_, sf_, dn_) \
  do{                                                                      \
    int nn_ = (n_) + 2*nwaves;                                             \
    rn0_ = 0; rn1_ = 0;                                                    \
    if (nn_ < N){ rn0_ = row_ptr[nn_]; rn1_ = row_ptr[nn_+1]; }            \
    e0_ = -1; e1_ = -1;                                                    \
    if ((n_) < N){                                                         \
      sf_ = m[(size_t)(n_)*8 + q2];                                        \
      dn_ = dis[n_];                                                       \
      int j0_ = (rp0_) + sub, j1_ = (rp0_) + 8 + sub;                      \
      if (j0_ < (rp1_)) e0_ = csr[j0_];                                    \
      if (j1_ < (rp1_)) e1_ = csr[j1_];                                    \
      if (e0_ >= 0) g0_ = m[(size_t)e0_*8 + q2];                           \
      if (e1_ >= 0) g1_ = m[(size_t)e1_*8 + q2];                           \
    }                                                                      \
  }while(0)

#define AGG_ACCRED(n_, rp0_, rp1_, e0_, e1_, g0_, g1_, sf_, dn_)           \
      float acc0=0.f,acc1=0.f,acc2=0.f,acc3=0.f;                           \
      float acc4=0.f,acc5=0.f,acc6=0.f,acc7=0.f;                           \
      if (e0_ >= 0) ACC8(g0_);                                             \
      if (e1_ >= 0) ACC8(g1_);                                             \
      for (int j_ = (rp0_) + 16 + sub; j_ < (rp1_); j_ += 8){              \
        h8v gx_ = m[(size_t)csr[j_]*8 + q2]; ACC8(gx_);                    \
      }                                                                    \
      RED3(acc0); RED3(acc1); RED3(acc2); RED3(acc3);                      \
      RED3(acc4); RED3(acc5); RED3(acc6); RED3(acc7);                      \
      float2 s01=__half22float2((sf_).a), s23=__half22float2((sf_).b);     \
      float2 s45=__half22float2((sf_).c), s67=__half22float2((sf_).d);     \
      float r0 = fmaxf(fmaf(acc0 + s01.x, dn_, bb0.x), 0.f);               \
      float r1 = fmaxf(fmaf(acc1 + s01.y, dn_, bb0.y), 0.f);               \
      float r2 = fmaxf(fmaf(acc2 + s23.x, dn_, bb0.z), 0.f);               \
      float r3 = fmaxf(fmaf(acc3 + s23.y, dn_, bb0.w), 0.f);               \
      float r4 = fmaxf(fmaf(acc4 + s45.x, dn_, bb1.x), 0.f);               \
      float r5 = fmaxf(fmaf(acc5 + s45.y, dn_, bb1.y), 0.f);               \
      float r6 = fmaxf(fmaf(acc6 + s67.x, dn_, bb1.z), 0.f);               \
      float r7 = fmaxf(fmaf(acc7 + s67.y, dn_, bb1.w), 0.f);

// REDUCE for the fused kernels: writes fp16(dn*h) into the wave's LDS tile
#define AGG_REDUCE(n_, rp0_, rp1_, e0_, e1_, g0_, g1_, sf_, dn_, i_)       \
  do{                                                                      \
    if ((n_) < N){                                                         \
      AGG_ACCRED(n_, rp0_, rp1_, e0_, e1_, g0_, g1_, sf_, dn_)             \
      if (sub == 0){                                                       \
        h8v hv_;                                                           \
        hv_.a = __floats2half2_rn(r0*(dn_), r1*(dn_));                     \
        hv_.b = __floats2half2_rn(r2*(dn_), r3*(dn_));                     \
        hv_.c = __floats2half2_rn(r4*(dn_), r5*(dn_));                     \
        hv_.d = __floats2half2_rn(r6*(dn_), r7*(dn_));                     \
        *(h8v*)(hlw + (i_)*72 + q2*8) = hv_;                               \
      }                                                                    \
    } else if (sub == 0){                                                  \
      h8v z_; z_.a = __floats2half2_rn(0.f, 0.f);                          \
      z_.b = z_.a; z_.c = z_.a; z_.d = z_.a;                               \
      *(h8v*)(hlw + (i_)*72 + q2*8) = z_;                                  \
    }                                                                      \
  }while(0)

// layers 2,3: pipelined gather + fused next-layer transform.
__global__ __launch_bounds__(256) void k_agg_fused(
    const h8v* __restrict__ m, const float* __restrict__ dis,
    const float* __restrict__ b, const float* __restrict__ Wn,
    const int* __restrict__ row_ptr, const int* __restrict__ csr,
    __half* __restrict__ mo, int N, int nwaves){
  __shared__ _Float16 hl[4][16*72];
  int t = threadIdx.x;
  int lane = t & 63, w = t >> 6;
  int sub = lane >> 3, q2 = lane & 7;
  int wid = (blockIdx.x*blockDim.x + t) >> 6;
  _Float16* hlw = hl[w];
  const float4* b4 = (const float4*)b;
  float4 bb0 = b4[q2*2], bb1 = b4[q2*2+1];

  int nA = wid,          rA0 = 0, rA1 = 0;
  int nB = wid + nwaves, rB0 = 0, rB1 = 0;
  if (nA < N){ rA0 = row_ptr[nA]; rA1 = row_ptr[nA+1]; }
  if (nB < N){ rB0 = row_ptr[nB]; rB1 = row_ptr[nB+1]; }
  int eA0, eA1, eB0, eB1, rnA0, rnA1, rnB0, rnB1;
  h8v gA0, gA1, sfA, gB0, gB1, sfB;
  float dnA = 0.f, dnB = 0.f;
  AGG_ISSUE(nA, rA0, rA1, rnA0, rnA1, eA0, eA1, gA0, gA1, sfA, dnA);
  for (int p = 0; p < 8; p++){
    AGG_ISSUE(nB, rB0, rB1, rnB0, rnB1, eB0, eB1, gB0, gB1, sfB, dnB);
    AGG_REDUCE(nA, rA0, rA1, eA0, eA1, gA0, gA1, sfA, dnA, 2*p);
    nA += 2*nwaves; rA0 = rnA0; rA1 = rnA1;
    if (p < 7)
      AGG_ISSUE(nA, rA0, rA1, rnA0, rnA1, eA0, eA1, gA0, gA1, sfA, dnA);
    AGG_REDUCE(nB, rB0, rB1, eB0, eB1, gB0, gB1, sfB, dnB, 2*p+1);
    nB += 2*nwaves; rB0 = rnB0; rB1 = rnB1;
  }
  LOAD_WFRAGS(Wn)            // loaded at epilogue: not live during main loop
  mfma_epilogue(hlw, wf, mo, wid, nwaves, N, lane);
}

// layer 4 (R8's measured-60us while-loop form): aggregation fused with output
// projection: per-node dot(h4, Wout) -> wave reduce -> atomic segment add.
__global__ __launch_bounds__(256) void k_agg64_out(
    const h8v* __restrict__ m, const float* __restrict__ dis,
    const float* __restrict__ b, const float* __restrict__ Wout,
    const int* __restrict__ batch,
    const int* __restrict__ row_ptr, const int* __restrict__ csr,
    float* gsum, int N, int nwaves){
  int lane = threadIdx.x & 63;
  int sub = lane >> 3, q2 = lane & 7;
  int n = (blockIdx.x*blockDim.x + threadIdx.x) >> 6;
  if (n >= N) return;
  int rp0 = row_ptr[n], rp1 = row_ptr[n+1];
  const float4* b4 = (const float4*)b;
  const float4* wo4 = (const float4*)Wout;
  while (true){
    int nn = n + nwaves;
    int np0 = 0, np1 = 0;
    if (nn < N){ np0 = row_ptr[nn]; np1 = row_ptr[nn+1]; }   // prefetch (indep)
    h8v sf = m[(size_t)n*8 + q2];                            // self row (indep)
    float dn = dis[n];
    int bg = batch[n];
    float acc0=0.f,acc1=0.f,acc2=0.f,acc3=0.f,acc4=0.f,acc5=0.f,acc6=0.f,acc7=0.f;
    int s1 = rp1;
    int j0 = rp0 + sub, j1 = rp0 + 8 + sub;
    if (j0 < s1){ h8v a = m[(size_t)csr[j0]*8 + q2]; ACC8(a); }
    if (j1 < s1){ h8v a = m[(size_t)csr[j1]*8 + q2]; ACC8(a); }
    for (int j = rp0 + 16 + sub; j < s1; j += 8){            // rare (deg>16)
      h8v a = m[(size_t)csr[j]*8 + q2]; ACC8(a);
    }
    RED3(acc0); RED3(acc1); RED3(acc2); RED3(acc3);
    RED3(acc4); RED3(acc5); RED3(acc6); RED3(acc7);
    float2 s01 = __half22float2(sf.a), s23 = __half22float2(sf.b);
    float2 s45 = __half22float2(sf.c), s67 = __half22float2(sf.d);
    float4 bb0 = b4[q2*2], bb1 = b4[q2*2+1];
    float4 w0 = wo4[q2*2], w1 = wo4[q2*2+1];
    float r0 = fmaxf(fmaf(acc0 + s01.x, dn, bb0.x), 0.f);
    float r1 = fmaxf(fmaf(acc1 + s01.y, dn, bb0.y), 0.f);
    float r2 = fmaxf(fmaf(acc2 + s23.x, dn, bb0.z), 0.f);
    float r3 = fmaxf(fmaf(acc3 + s23.y, dn, bb0.w), 0.f);
    float r4 = fmaxf(fmaf(acc4 + s45.x, dn, bb1.x), 0.f);
    float r5 = fmaxf(fmaf(acc5 + s45.y, dn, bb1.y), 0.f);
    float r6 = fmaxf(fmaf(acc6 + s67.x, dn, bb1.z), 0.f);
    float r7 = fmaxf(fmaf(acc7 + s67.y, dn, bb1.w), 0.f);
    float p = r0*w0.x + r1*w0.y + r2*w0.z + r3*w0.w
            + r4*w1.x + r5*w1.y + r6*w1.z + r7*w1.w;
    p += __shfl_xor(p,1,64); p += __shfl_xor(p,2,64); p += __shfl_xor(p,4,64);
    if (lane == 0) atomicAdd(&gsum[bg], p);
    if (nn >= N) break;
    n = nn; rp0 = np0; rp1 = np1;
  }
}

// final: per-graph count via binary search on SORTED batch (no atomics),
// then mean + bias.
__global__ void k_final(const float* __restrict__ gsum, const int* __restrict__ batch,
                        const float* __restrict__ bout, float* __restrict__ out,
                        int G, int N){
  int g = blockIdx.x*blockDim.x + threadIdx.x;
  if (g >= G) return;
  int lo = 0, hi = N;
  while (lo < hi){ int mid = (lo+hi)>>1; if (batch[mid] <  g) lo = mid+1; else hi = mid; }
  int lb = lo;
  lo = 0; hi = N;
  while (lo < hi){ int mid = (lo+hi)>>1; if (batch[mid] <= g) lo = mid+1; else hi = mid; }
  int c = lo - lb;
  out[g] = gsum[g]/(float)(c > 0 ? c : 1) + bout[0];
}

extern "C" void kernel_launch(void* const* d_in, const int* in_sizes, int n_in,
                              void* d_out, int out_size, void* d_ws, size_t ws_size,
                              hipStream_t stream){
  const float* x    = (const float*)d_in[0];
  const int*   ei   = (const int*)d_in[1];
  const int*   batch= (const int*)d_in[2];
  const float* W1 = (const float*)d_in[3];  const float* b1 = (const float*)d_in[4];
  const float* W2 = (const float*)d_in[5];  const float* b2 = (const float*)d_in[6];
  const float* W3 = (const float*)d_in[7];  const float* b3 = (const float*)d_in[8];
  const float* W4 = (const float*)d_in[9];  const float* b4 = (const float*)d_in[10];
  const float* Wout = (const float*)d_in[11]; const float* bout = (const float*)d_in[12];
  float* out = (float*)d_out;

  const int N = in_sizes[0]/9;
  const int E = in_sizes[1]/2;
  const int G = out_size;
  const int* src = ei;        // edge_index[0]
  const int* dst = ei + E;    // edge_index[1]

  char* ws = (char*)d_ws;
  size_t off = 0;
  auto alloc = [&](size_t bytes){ void* p = ws + off; off = align256(off + bytes); return p; };
  int*   row_ptr  = (int*)  alloc((size_t)(N+1)*4);
  int*   csr      = (int*)  alloc((size_t)E*4);
  float* dis      = (float*)alloc((size_t)N*4);
  const int NBK = (N + 127)/128;        // 782 buckets of 128 dst nodes
  const int NC  = (E + CHUNK-1)/CHUNK;  // 489 sort chunks
  int*   hoffC    = (int*)  alloc((size_t)NC*783*4);   // per-chunk bucket offsets
  int*   btot     = (int*)  alloc((size_t)NBK*4);
  int*   bbase    = (int*)  alloc((size_t)NBK*4);
  float* gsum     = (float*)alloc((size_t)G*4);
  __half* mA      = (__half*)alloc((size_t)N*64*2);  // fp16 message ping
  __half* mB      = (__half*)alloc((size_t)N*64*2);  // fp16 message pong
  // aliases (lifetimes verified):
  int*   binned   = (int*)mA;              // 4MB <= 12.8MB; dead after k_gather2
  float* xs       = (float*)mB;            // 3.6MB; dead after k_agg9
  float* xagg     = xs + (size_t)N*9;      // 3.6MB; dead after k_lin1_fused
  // m2 = mA (written by lin1_fused, after binned dead)
  // m3 = mB (written by aggF layer2, after xs/xagg dead)
  // m4 = mA (written by aggF layer3, after m2 dead)

  const int AGG_BLOCKS = 2048;             // persistent: 8 blocks/CU on 256 CUs
  const int AGG_WAVES  = AGG_BLOCKS*4;     // 8192 waves; 16*8192 >= N (batch=16)

  k_zero     <<<(G+255)/256, 256, 0, stream>>>(gsum, G);
  k_sortchunk<<<NC, 256, 0, stream>>>(src, dst, binned, hoffC, E);
  k_bktsum   <<<NBK, 256, 0, stream>>>(hoffC, btot, NC, NBK);
  k_bktscan  <<<1, 1024, 0, stream>>>(btot, bbase, row_ptr, NBK, N, E);
  k_gather2  <<<NBK, 256, 0, stream>>>(binned, hoffC, bbase, row_ptr, dis, csr, N, NC);

  // layer 1: premultiply, aggregate (9 feats), transform fused with m2 build
  k_premul<<<(N*9+255)/256, 256, 0, stream>>>(x, dis, xs, N);
  k_agg9  <<<(N*9+255)/256, 256, 0, stream>>>(xs, dis, row_ptr, csr, xagg, N);
  k_lin1_fused<<<AGG_BLOCKS, 256, 0, stream>>>(xagg, W1, b1, dis, W2, mA, N, AGG_WAVES);

  // layer 2: aggregate m2 -> h2 (regs) -> m3   (uses b2, W3)
  k_agg_fused<<<AGG_BLOCKS, 256, 0, stream>>>((const h8v*)mA, dis, b2, W3,
                                              row_ptr, csr, mB, N, AGG_WAVES);
  // layer 3: aggregate m3 -> h3 (regs) -> m4   (uses b3, W4)
  k_agg_fused<<<AGG_BLOCKS, 256, 0, stream>>>((const h8v*)mB, dis, b3, W4,
                                              row_ptr, csr, mA, N, AGG_WAVES);
  // layer 4: aggregate m4 -> h4 (regs) -> Wout dot -> pooled sums
  k_agg64_out<<<AGG_BLOCKS, 256, 0, stream>>>((const h8v*)mA, dis, b4, Wout, batch,
                                              row_ptr, csr, gsum, N, AGG_WAVES);

  k_final<<<(G+255)/256, 256, 0, stream>>>(gsum, batch, bout, out, G, N);
}

// Round 14
// 301.922 us; speedup vs baseline: 1.2579x; 1.0207x over previous
//
#include <hip/hip_runtime.h>
#include <hip/hip_fp16.h>

// GCN: 4x (gcn_conv + relu) + global mean pool + linear out.
// N=100000 nodes, E=1000000 edges, G=4096 graphs, F_IN=9, H=64.
// R1: wave-per-node gather MLP restructure; layer-4 agg fused with out-proj.
// R2 (FAILED, 237us): global bucket-cursor scatter -- atomic contention.
// R3: scatter-free CSR build (LDS chunk sort + single-writer bucket gather).
// R4: fp16 message rows.  FETCH halved, time flat => NOT byte-bound.
// R5: 8x8 subgroups + persistent waves + row_ptr prefetch: 72->63us/agg.
// R6 (FAILED): edge-centric LDS-atomic aggregation -- LDS atomics serialized.
// R7: standalone MFMA lin64 net-negative, but VALIDATED 16x16x32_f16 layouts.
// R8: lin64 deleted; transform fused into agg epilogue via MFMA.  451 -> 379us.
// R9-R11: 2-deep A/B pipeline: agg_fused 65->47 (keep); agg64_out 60->70
//     (regressed -- fixed-16 batch = 24% predicated-waste iterations).
// R12: selective revert + premul-into-scanC: 341us.
// R13/R14: deg-free graph build; k_bktsum reshaped to block-per-bucket: 308us.
// R16: (1) agg64_out rotate-pipeline: 2-deep A/B in WHILE form (early exit,
//     zero waste; bb/w loaded in REDUCE to cap VGPR) -- retests R11's pipeline
//     with the waste mechanism removed.  (2) gather2 single-global-pass: LDS
//     edge staging (SCAP=3072 = 50 sigma; global-rewalk fallback), premul
//     folded into its tail.  (3) k_zero folded into k_bktsum.  13->10 kernels.

static inline size_t align256(size_t x){ return (x + 255) & ~size_t(255); }

#define CHUNK 2048          // edges per sort chunk
#define SCAP  3072          // gather2 LDS edge-staging capacity (12KB)

struct __align__(8)  h4v { __half2 a, b; };        // 4 halves = 8B
struct __align__(16) h8v { __half2 a, b, c, d; };  // 8 halves = 16B (agg gather)

typedef _Float16 f16x8 __attribute__((ext_vector_type(8)));
typedef float    f32x4 __attribute__((ext_vector_type(4)));

// pass 1: sort a 2048-edge chunk by bucket entirely in LDS, emit the sorted
// image (coalesced) + the chunk's 783-entry bucket-offset row (coalesced).
// Entry packed as (src<<7)|(dst&127); src < 2^17 fits.
__global__ __launch_bounds__(256) void k_sortchunk(
    const int* __restrict__ src, const int* __restrict__ dst,
    int* __restrict__ binned, int* __restrict__ hoffC, int E){
  __shared__ int hcnt[1024];            // 782 used; padded pow2 for scan
  __shared__ int simg[CHUNK];
  int c = blockIdx.x, t = threadIdx.x;
  int e0 = c*CHUNK;
  int cnt = E - e0; if (cnt > CHUNK) cnt = CHUNK;

  for (int i = t; i < 1024; i += 256) hcnt[i] = 0;
  __syncthreads();

  int b_[8], r_[8], v_[8];              // static-indexed (stays in VGPRs)
  #pragma unroll
  for (int j = 0; j < 8; j++){
    int i = t + j*256;
    if (i < cnt){
      int d = dst[e0+i];
      int s = src[e0+i];
      int b = d >> 7;
      b_[j] = b;
      r_[j] = atomicAdd(&hcnt[b], 1);
      v_[j] = (s << 7) | (d & 127);
    } else b_[j] = -1;
  }
  __syncthreads();

  // in-place Hillis-Steele inclusive scan of hcnt[0..1023]
  int own[4];
  #pragma unroll
  for (int j = 0; j < 4; j++) own[j] = hcnt[t + j*256];
  for (int off = 1; off < 1024; off <<= 1){
    int nv[4];
    #pragma unroll
    for (int j = 0; j < 4; j++){
      int i = t + j*256;
      nv[j] = hcnt[i] + ((i >= off) ? hcnt[i-off] : 0);
    }
    __syncthreads();
    #pragma unroll
    for (int j = 0; j < 4; j++) hcnt[t + j*256] = nv[j];
    __syncthreads();
  }
  // inclusive -> exclusive
  #pragma unroll
  for (int j = 0; j < 4; j++) hcnt[t + j*256] -= own[j];
  __syncthreads();

  // emit bucket-offset row (hcnt[782] == cnt since buckets >=782 are empty)
  for (int i = t; i < 783; i += 256) hoffC[c*783 + i] = hcnt[i];

  // place edges bucket-major in LDS
  #pragma unroll
  for (int j = 0; j < 8; j++)
    if (b_[j] >= 0) simg[hcnt[b_[j]] + r_[j]] = v_[j];
  __syncthreads();

  // coalesced stream-out of the sorted chunk image
  for (int i = t; i < cnt; i += 256) binned[e0 + i] = simg[i];
}

// bucket totals: one block PER bucket; 256 threads stride the chunks and
// tree-reduce in LDS.  Also zeroes gsum (grid covers G easily).
__global__ __launch_bounds__(256) void k_bktsum(
    const int* __restrict__ hoffC, int* __restrict__ btot,
    float* __restrict__ gsum, int NC, int NBK, int G){
  __shared__ int s[256];
  int b = blockIdx.x, t = threadIdx.x;
  int gid = b*256 + t;
  if (gid < G) gsum[gid] = 0.f;
  int tot = 0;
  for (int c = t; c < NC; c += 256)
    tot += hoffC[c*783 + b + 1] - hoffC[c*783 + b];
  s[t] = tot; __syncthreads();
  for (int off = 128; off > 0; off >>= 1){
    if (t < off) s[t] += s[t+off];
    __syncthreads();
  }
  if (t == 0) btot[b] = s[0];
}

// single-block exclusive scan of bucket totals (NBK=782 <= 1024) -> bbase;
// also writes the row_ptr[N]=E sentinel.
__global__ __launch_bounds__(1024) void k_bktscan(
    const int* __restrict__ btot, int* __restrict__ bbase,
    int* __restrict__ row_ptr, int NBK, int N, int E){
  __shared__ int s[1024];
  int t = threadIdx.x;
  int v = (t < NBK) ? btot[t] : 0;
  s[t] = v; __syncthreads();
  for (int off = 1; off < 1024; off <<= 1){
    int add = (t >= off) ? s[t-off] : 0; __syncthreads();
    s[t] += add; __syncthreads();
  }
  if (t < NBK) bbase[t] = s[t] - v;
  if (t == 0) row_ptr[N] = E;
}

// pass 2: WG per bucket, SINGLE global pass over the bucket's segments:
//   pass A: stage edges into LDS (per-segment scount base) + count degrees
//   scan -> row_ptr, dis, cursors; fused premul writes xs = x*dis
//   pass B: place from LDS staging (global-rewalk fallback if overflow).
__global__ __launch_bounds__(256) void k_gather2(
    const int* __restrict__ binned, const int* __restrict__ hoffC,
    const int* __restrict__ bbase, const float* __restrict__ x,
    int* __restrict__ row_ptr, float* __restrict__ dis,
    float* __restrict__ xs, int* __restrict__ csr, int N, int NC){
  __shared__ int lcur[128];
  __shared__ int lscan[128];
  __shared__ float ldis[128];
  __shared__ int stage[SCAP];
  __shared__ int scount;
  int b = blockIdx.x, t = threadIdx.x;
  int n0 = b << 7;
  int nn = N - n0; if (nn > 128) nn = 128;
  if (t < 128) lcur[t] = 0;
  if (t == 0) scount = 0;
  __syncthreads();
  // pass A: stage + degree count
  for (int c = t; c < NC; c += 256){
    int o0 = hoffC[c*783 + b];
    int o1 = hoffC[c*783 + b + 1];
    int len = o1 - o0;
    if (len > 0){
      int base = atomicAdd(&scount, len);
      int sbase = c*CHUNK;
      for (int k = 0; k < len; k++){
        int v = binned[sbase + o0 + k];
        atomicAdd(&lcur[v & 127], 1);
        int pos = base + k;
        if (pos < SCAP) stage[pos] = v;
      }
    }
  }
  __syncthreads();
  int degv = (t < 128) ? lcur[t] : 0;
  if (t < 128) lscan[t] = degv;
  __syncthreads();
  for (int off = 1; off < 128; off <<= 1){
    int add = (t < 128 && t >= off) ? lscan[t-off] : 0;
    __syncthreads();
    if (t < 128) lscan[t] += add;
    __syncthreads();
  }
  int bb = bbase[b];
  if (t < nn){
    int row = bb + lscan[t] - degv;        // exclusive
    row_ptr[n0 + t] = row;
    float dv = rsqrtf((float)(degv + 1));  // +1 self-loop
    dis[n0 + t] = dv;
    ldis[t] = dv;
    lcur[t] = row;                          // cursor for pass B
  }
  __syncthreads();
  // fused premul: xs = x * dis for this block's nodes (coalesced)
  for (int i = t; i < nn*9; i += 256)
    xs[(size_t)n0*9 + i] = x[(size_t)n0*9 + i] * ldis[i/9];
  // pass B: place
  int sc = scount;
  if (sc <= SCAP){
    for (int i = t; i < sc; i += 256){
      int v = stage[i];
      int pos = atomicAdd(&lcur[v & 127], 1);
      csr[pos] = v >> 7;
    }
  } else {
    // overflow fallback (statistically impossible: SCAP ~ 50 sigma): rewalk
    for (int c = t; c < NC; c += 256){
      int o0 = hoffC[c*783 + b];
      int o1 = hoffC[c*783 + b + 1];
      int sbase = c*CHUNK;
      for (int k = o0; k < o1; k++){
        int v = binned[sbase + k];
        int pos = atomicAdd(&lcur[v & 127], 1);
        csr[pos] = v >> 7;
      }
    }
  }
}

// layer-1 aggregation over xs (9 features): thread per (node, feature), unroll-4 MLP
__global__ void k_agg9(const float* __restrict__ xs, const float* __restrict__ dis,
                       const int* __restrict__ row_ptr, const int* __restrict__ csr,
                       float* __restrict__ xagg, int N){
  int tid = blockIdx.x*blockDim.x + threadIdx.x;
  if (tid >= N*9) return;
  int n = tid/9, f = tid - n*9;
  float dn = dis[n];
  int s0 = row_ptr[n], s1 = row_ptr[n+1];
  float a0 = xs[tid];                 // self-loop term (x[n]*dis[n])
  float a1 = 0.f, a2 = 0.f, a3 = 0.f;
  int j = s0;
  for (; j + 3 < s1; j += 4){
    int e0 = csr[j], e1 = csr[j+1], e2 = csr[j+2], e3 = csr[j+3];
    a0 += xs[e0*9+f];
    a1 += xs[e1*9+f];
    a2 += xs[e2*9+f];
    a3 += xs[e3*9+f];
  }
  for (; j < s1; j++) a0 += xs[csr[j]*9+f];
  xagg[tid] = ((a0+a1)+(a2+a3))*dn;
}

// MFMA epilogue shared by the fused kernels.  hlw = this wave's 16x72-half
// LDS tile (row i = node wid + i*nwaves, cols 0..63 = dis*h fp16, 64..71 pad).
__device__ __forceinline__ void mfma_epilogue(
    const _Float16* hlw, const f16x8 (&wf)[4][2],
    __half* __restrict__ mo, int wid, int nwaves, int N, int lane){
  int lm = lane & 15, lk = lane >> 4;
  f16x8 hb0 = *(const f16x8*)(hlw + lm*72 + lk*8);
  f16x8 hb1 = *(const f16x8*)(hlw + lm*72 + 32 + lk*8);
  int node = wid + lm*nwaves;
  bool ok = (node < N);
  __half* row = mo + (size_t)node*64;
  #pragma unroll
  for (int ft = 0; ft < 4; ft++){
    f32x4 acc = {0.f, 0.f, 0.f, 0.f};
    acc = __builtin_amdgcn_mfma_f32_16x16x32_f16(wf[ft][0], hb0, acc, 0, 0, 0);
    acc = __builtin_amdgcn_mfma_f32_16x16x32_f16(wf[ft][1], hb1, acc, 0, 0, 0);
    if (ok){
      h4v o;
      o.a = __floats2half2_rn(acc[0], acc[1]);
      o.b = __floats2half2_rn(acc[2], acc[3]);
      *(h4v*)(row + ft*16 + lk*4) = o;
    }
  }
}

#define LOAD_WFRAGS(Wn)                                                    \
  f16x8 wf[4][2];                                                          \
  { int lm_ = lane & 15, lk_ = lane >> 4;                                  \
    _Pragma("unroll") for (int ft = 0; ft < 4; ft++)                       \
    _Pragma("unroll") for (int kb = 0; kb < 2; kb++)                       \
    _Pragma("unroll") for (int j = 0; j < 8; j++)                          \
      wf[ft][kb][j] = (_Float16)Wn[(kb*32 + lk_*8 + j)*64 + ft*16 + lm_]; }

// layer 1 transform fused with next-layer message build:
// h1 = relu(xagg@W1+b1); m2 = fp16((dis*h1) @ W2).  h1 never stored.
__global__ __launch_bounds__(256) void k_lin1_fused(
    const float* __restrict__ xagg, const float* __restrict__ W1,
    const float* __restrict__ b1, const float* __restrict__ dis,
    const float* __restrict__ W2, __half* __restrict__ mo, int N, int nwaves){
  __shared__ float W1l[576];
  __shared__ float b1l[64];
  __shared__ _Float16 hl[4][16*72];
  int t = threadIdx.x;
  for (int i = t; i < 576; i += 256) W1l[i] = W1[i];
  if (t < 64) b1l[t] = b1[t];
  __syncthreads();
  int lane = t & 63, w = t >> 6;
  int wid = (blockIdx.x*blockDim.x + t) >> 6;
  LOAD_WFRAGS(W2)
  _Float16* hlw = hl[w];
  for (int i = 0; i < 16; i++){
    int n = wid + i*nwaves;
    _Float16 hv = (_Float16)0.f;
    if (n < N){
      float acc = b1l[lane];
      #pragma unroll
      for (int k = 0; k < 9; k++) acc = fmaf(xagg[n*9+k], W1l[k*64+lane], acc);
      hv = (_Float16)(fmaxf(acc, 0.f) * dis[n]);
    }
    hlw[i*72 + lane] = hv;
  }
  mfma_epilogue(hlw, wf, mo, wid, nwaves, N, lane);
}

// NOTE: param is g_ (NOT `a`): body reads members .a/.b/.c/.d and the
// preprocessor would substitute a same-named parameter into member tokens.
#define ACC8(g_)  do{ float2 t_;                                   \
  t_ = __half22float2((g_).a); acc0 += t_.x; acc1 += t_.y;         \
  t_ = __half22float2((g_).b); acc2 += t_.x; acc3 += t_.y;         \
  t_ = __half22float2((g_).c); acc4 += t_.x; acc5 += t_.y;         \
  t_ = __half22float2((g_).d); acc6 += t_.x; acc7 += t_.y; }while(0)

#define RED3(v)  do{ v += __shfl_xor(v, 8,64);                     \
                     v += __shfl_xor(v,16,64);                     \
                     v += __shfl_xor(v,32,64); }while(0)

// --- pipeline stages (named register sets; no runtime-indexed arrays) ---
// ISSUE for agg_fused: prefetch row_ptr 2 ahead (A/B streams advance by
// 2*nwaves), load self row + dis, csr indices, launch the node's 16 gathers.
#define AGG_ISSUE(n_, rp0_, rp1_, rn0_, rn1_, e0_, e1_, g0_, g1_, sf_, dn_) \
  do{                                                                      \
    int nn_ = (n_) + 2*nwaves;                                             \
    rn0_ = 0; rn1_ = 0;                                                    \
    if (nn_ < N){ rn0_ = row_ptr[nn_]; rn1_ = row_ptr[nn_+1]; }            \
    e0_ = -1; e1_ = -1;                                                    \
    if ((n_) < N){                                                         \
      sf_ = m[(size_t)(n_)*8 + q2];                                        \
      dn_ = dis[n_];                                                       \
      int j0_ = (rp0_) + sub, j1_ = (rp0_) + 8 + sub;                      \
      if (j0_ < (rp1_)) e0_ = csr[j0_];                                    \
      if (j1_ < (rp1_)) e1_ = csr[j1_];                                    \
      if (e0_ >= 0) g0_ = m[(size_t)e0_*8 + q2];                           \
      if (e1_ >= 0) g1_ = m[(size_t)e1_*8 + q2];                           \
    }                                                                      \
  }while(0)

#define AGG_ACCRED(n_, rp0_, rp1_, e0_, e1_, g0_, g1_, sf_, dn_)           \
      float acc0=0.f,acc1=0.f,acc2=0.f,acc3=0.f;                           \
      float acc4=0.f,acc5=0.f,acc6=0.f,acc7=0.f;                           \
      if (e0_ >= 0) ACC8(g0_);                                             \
      if (e1_ >= 0) ACC8(g1_);                                             \
      for (int j_ = (rp0_) + 16 + sub; j_ < (rp1_); j_ += 8){              \
        h8v gx_ = m[(size_t)csr[j_]*8 + q2]; ACC8(gx_);                    \
      }                                                                    \
      RED3(acc0); RED3(acc1); RED3(acc2); RED3(acc3);                      \
      RED3(acc4); RED3(acc5); RED3(acc6); RED3(acc7);                      \
      float2 s01=__half22float2((sf_).a), s23=__half22float2((sf_).b);     \
      float2 s45=__half22float2((sf_).c), s67=__half22float2((sf_).d);     \
      float r0 = fmaxf(fmaf(acc0 + s01.x, dn_, bb0.x), 0.f);               \
      float r1 = fmaxf(fmaf(acc1 + s01.y, dn_, bb0.y), 0.f);               \
      float r2 = fmaxf(fmaf(acc2 + s23.x, dn_, bb0.z), 0.f);               \
      float r3 = fmaxf(fmaf(acc3 + s23.y, dn_, bb0.w), 0.f);               \
      float r4 = fmaxf(fmaf(acc4 + s45.x, dn_, bb1.x), 0.f);               \
      float r5 = fmaxf(fmaf(acc5 + s45.y, dn_, bb1.y), 0.f);               \
      float r6 = fmaxf(fmaf(acc6 + s67.x, dn_, bb1.z), 0.f);               \
      float r7 = fmaxf(fmaf(acc7 + s67.y, dn_, bb1.w), 0.f);

// REDUCE for the fused kernels: writes fp16(dn*h) into the wave's LDS tile
#define AGG_REDUCE(n_, rp0_, rp1_, e0_, e1_, g0_, g1_, sf_, dn_, i_)       \
  do{                                                                      \
    if ((n_) < N){                                                         \
      AGG_ACCRED(n_, rp0_, rp1_, e0_, e1_, g0_, g1_, sf_, dn_)             \
      if (sub == 0){                                                       \
        h8v hv_;                                                           \
        hv_.a = __floats2half2_rn(r0*(dn_), r1*(dn_));                     \
        hv_.b = __floats2half2_rn(r2*(dn_), r3*(dn_));                     \
        hv_.c = __floats2half2_rn(r4*(dn_), r5*(dn_));                     \
        hv_.d = __floats2half2_rn(r6*(dn_), r7*(dn_));                     \
        *(h8v*)(hlw + (i_)*72 + q2*8) = hv_;                               \
      }                                                                    \
    } else if (sub == 0){                                                  \
      h8v z_; z_.a = __floats2half2_rn(0.f, 0.f);                          \
      z_.b = z_.a; z_.c = z_.a; z_.d = z_.a;                               \
      *(h8v*)(hlw + (i_)*72 + q2*8) = z_;                                  \
    }                                                                      \
  }while(0)

// ISSUE for agg64_out's rotate pipeline: prefetch row_ptr only 1*nwaves
// ahead (the other stream's ISSUE consumes it one half-step later).
#define OUT_ISSUE(n_, rp0_, rp1_, rn0_, rn1_, e0_, e1_, g0_, g1_, sf_, dn_, bg_) \
  do{                                                                      \
    int pn_ = (n_) + nwaves;                                               \
    rn0_ = 0; rn1_ = 0;                                                    \
    if (pn_ < N){ rn0_ = row_ptr[pn_]; rn1_ = row_ptr[pn_+1]; }            \
    sf_ = m[(size_t)(n_)*8 + q2];                                          \
    dn_ = dis[n_];                                                         \
    bg_ = batch[n_];                                                       \
    e0_ = -1; e1_ = -1;                                                    \
    int j0_ = (rp0_) + sub, j1_ = (rp0_) + 8 + sub;                        \
    if (j0_ < (rp1_)) e0_ = csr[j0_];                                      \
    if (j1_ < (rp1_)) e1_ = csr[j1_];                                      \
    if (e0_ >= 0) g0_ = m[(size_t)e0_*8 + q2];                             \
    if (e1_ >= 0) g1_ = m[(size_t)e1_*8 + q2];                             \
  }while(0)

// REDUCE for layer 4: bb/w loaded HERE (L1-hot, keeps main-loop VGPR low)
#define OUT_REDUCE(n_, rp0_, rp1_, e0_, e1_, g0_, g1_, sf_, dn_, bg_)      \
  do{                                                                      \
    float4 bb0 = b4[q2*2], bb1 = b4[q2*2+1];                               \
    float4 w0 = wo4[q2*2], w1 = wo4[q2*2+1];                               \
    AGG_ACCRED(n_, rp0_, rp1_, e0_, e1_, g0_, g1_, sf_, dn_)               \
    float p_ = r0*w0.x + r1*w0.y + r2*w0.z + r3*w0.w                       \
             + r4*w1.x + r5*w1.y + r6*w1.z + r7*w1.w;                      \
    p_ += __shfl_xor(p_,1,64); p_ += __shfl_xor(p_,2,64);                  \
    p_ += __shfl_xor(p_,4,64);                                             \
    if (lane == 0) atomicAdd(&gsum[bg_], p_);                              \
  }while(0)

// layers 2,3: pipelined gather + fused next-layer transform.
__global__ __launch_bounds__(256) void k_agg_fused(
    const h8v* __restrict__ m, const float* __restrict__ dis,
    const float* __restrict__ b, const float* __restrict__ Wn,
    const int* __restrict__ row_ptr, const int* __restrict__ csr,
    __half* __restrict__ mo, int N, int nwaves){
  __shared__ _Float16 hl[4][16*72];
  int t = threadIdx.x;
  int lane = t & 63, w = t >> 6;
  int sub = lane >> 3, q2 = lane & 7;
  int wid = (blockIdx.x*blockDim.x + t) >> 6;
  _Float16* hlw = hl[w];
  const float4* b4 = (const float4*)b;
  float4 bb0 = b4[q2*2], bb1 = b4[q2*2+1];

  int nA = wid,          rA0 = 0, rA1 = 0;
  int nB = wid + nwaves, rB0 = 0, rB1 = 0;
  if (nA < N){ rA0 = row_ptr[nA]; rA1 = row_ptr[nA+1]; }
  if (nB < N){ rB0 = row_ptr[nB]; rB1 = row_ptr[nB+1]; }
  int eA0, eA1, eB0, eB1, rnA0, rnA1, rnB0, rnB1;
  h8v gA0, gA1, sfA, gB0, gB1, sfB;
  float dnA = 0.f, dnB = 0.f;
  AGG_ISSUE(nA, rA0, rA1, rnA0, rnA1, eA0, eA1, gA0, gA1, sfA, dnA);
  for (int p = 0; p < 8; p++){
    AGG_ISSUE(nB, rB0, rB1, rnB0, rnB1, eB0, eB1, gB0, gB1, sfB, dnB);
    AGG_REDUCE(nA, rA0, rA1, eA0, eA1, gA0, gA1, sfA, dnA, 2*p);
    nA += 2*nwaves; rA0 = rnA0; rA1 = rnA1;
    if (p < 7)
      AGG_ISSUE(nA, rA0, rA1, rnA0, rnA1, eA0, eA1, gA0, gA1, sfA, dnA);
    AGG_REDUCE(nB, rB0, rB1, eB0, eB1, gB0, gB1, sfB, dnB, 2*p+1);
    nB += 2*nwaves; rB0 = rnB0; rB1 = rnB1;
  }
  LOAD_WFRAGS(Wn)            // loaded at epilogue: not live during main loop
  mfma_epilogue(hlw, wf, mo, wid, nwaves, N, lane);
}

// layer 4: rotate-pipelined while-loop (2-deep A/B, early exit, NO fixed-16
// waste -- retests R11's pipeline with the waste mechanism removed).
__global__ __launch_bounds__(256) void k_agg64_out(
    const h8v* __restrict__ m, const float* __restrict__ dis,
    const float* __restrict__ b, const float* __restrict__ Wout,
    const int* __restrict__ batch,
    const int* __restrict__ row_ptr, const int* __restrict__ csr,
    float* gsum, int N, int nwaves){
  int lane = threadIdx.x & 63;
  int sub = lane >> 3, q2 = lane & 7;
  int wid = (blockIdx.x*blockDim.x + threadIdx.x) >> 6;
  if (wid >= N) return;
  const float4* b4 = (const float4*)b;
  const float4* wo4 = (const float4*)Wout;

  int nA = wid;
  int rA0 = row_ptr[nA], rA1 = row_ptr[nA+1];
  int rnA0, rnA1, rnB0, rnB1;
  int eA0, eA1, eB0, eB1, bgA, bgB;
  h8v gA0, gA1, sfA, gB0, gB1, sfB;
  float dnA, dnB;
  int rB0, rB1;
  OUT_ISSUE(nA, rA0, rA1, rnA0, rnA1, eA0, eA1, gA0, gA1, sfA, dnA, bgA);
  for(;;){
    int nB = nA + nwaves;
    if (nB < N){
      rB0 = rnA0; rB1 = rnA1;
      OUT_ISSUE(nB, rB0, rB1, rnB0, rnB1, eB0, eB1, gB0, gB1, sfB, dnB, bgB);
    }
    OUT_REDUCE(nA, rA0, rA1, eA0, eA1, gA0, gA1, sfA, dnA, bgA);
    if (nB >= N) return;
    int nA2 = nB + nwaves;
    if (nA2 < N){
      nA = nA2;
      rA0 = rnB0; rA1 = rnB1;
      OUT_ISSUE(nA, rA0, rA1, rnA0, rnA1, eA0, eA1, gA0, gA1, sfA, dnA, bgA);
    }
    OUT_REDUCE(nB, rB0, rB1, eB0, eB1, gB0, gB1, sfB, dnB, bgB);
    if (nA2 >= N) return;
  }
}

// final: per-graph count via binary search on SORTED batch (no atomics),
// then mean + bias.
__global__ void k_final(const float* __restrict__ gsum, const int* __restrict__ batch,
                        const float* __restrict__ bout, float* __restrict__ out,
                        int G, int N){
  int g = blockIdx.x*blockDim.x + threadIdx.x;
  if (g >= G) return;
  int lo = 0, hi = N;
  while (lo < hi){ int mid = (lo+hi)>>1; if (batch[mid] <  g) lo = mid+1; else hi = mid; }
  int lb = lo;
  lo = 0; hi = N;
  while (lo < hi){ int mid = (lo+hi)>>1; if (batch[mid] <= g) lo = mid+1; else hi = mid; }
  int c = lo - lb;
  out[g] = gsum[g]/(float)(c > 0 ? c : 1) + bout[0];
}

extern "C" void kernel_launch(void* const* d_in, const int* in_sizes, int n_in,
                              void* d_out, int out_size, void* d_ws, size_t ws_size,
                              hipStream_t stream){
  const float* x    = (const float*)d_in[0];
  const int*   ei   = (const int*)d_in[1];
  const int*   batch= (const int*)d_in[2];
  const float* W1 = (const float*)d_in[3];  const float* b1 = (const float*)d_in[4];
  const float* W2 = (const float*)d_in[5];  const float* b2 = (const float*)d_in[6];
  const float* W3 = (const float*)d_in[7];  const float* b3 = (const float*)d_in[8];
  const float* W4 = (const float*)d_in[9];  const float* b4 = (const float*)d_in[10];
  const float* Wout = (const float*)d_in[11]; const float* bout = (const float*)d_in[12];
  float* out = (float*)d_out;

  const int N = in_sizes[0]/9;
  const int E = in_sizes[1]/2;
  const int G = out_size;
  const int* src = ei;        // edge_index[0]
  const int* dst = ei + E;    // edge_index[1]

  char* ws = (char*)d_ws;
  size_t off = 0;
  auto alloc = [&](size_t bytes){ void* p = ws + off; off = align256(off + bytes); return p; };
  int*   row_ptr  = (int*)  alloc((size_t)(N+1)*4);
  int*   csr      = (int*)  alloc((size_t)E*4);
  float* dis      = (float*)alloc((size_t)N*4);
  const int NBK = (N + 127)/128;        // 782 buckets of 128 dst nodes
  const int NC  = (E + CHUNK-1)/CHUNK;  // 489 sort chunks
  int*   hoffC    = (int*)  alloc((size_t)NC*783*4);   // per-chunk bucket offsets
  int*   btot     = (int*)  alloc((size_t)NBK*4);
  int*   bbase    = (int*)  alloc((size_t)NBK*4);
  float* gsum     = (float*)alloc((size_t)G*4);
  __half* mA      = (__half*)alloc((size_t)N*64*2);  // fp16 message ping
  __half* mB      = (__half*)alloc((size_t)N*64*2);  // fp16 message pong
  // aliases (lifetimes verified):
  int*   binned   = (int*)mA;              // 4MB <= 12.8MB; dead after k_gather2
  float* xs       = (float*)mB;            // 3.6MB; written by gather2, dead after agg9
  float* xagg     = xs + (size_t)N*9;      // 3.6MB; dead after k_lin1_fused
  // m2 = mA (written by lin1_fused, after binned dead)
  // m3 = mB (written by aggF layer2, after xs/xagg dead)
  // m4 = mA (written by aggF layer3, after m2 dead)

  const int AGG_BLOCKS = 2048;             // persistent: 8 blocks/CU on 256 CUs
  const int AGG_WAVES  = AGG_BLOCKS*4;     // 8192 waves; 16*8192 >= N (batch=16)

  k_sortchunk<<<NC, 256, 0, stream>>>(src, dst, binned, hoffC, E);
  k_bktsum   <<<NBK, 256, 0, stream>>>(hoffC, btot, gsum, NC, NBK, G);
  k_bktscan  <<<1, 1024, 0, stream>>>(btot, bbase, row_ptr, NBK, N, E);
  k_gather2  <<<NBK, 256, 0, stream>>>(binned, hoffC, bbase, x,
                                       row_ptr, dis, xs, csr, N, NC);

  // layer 1: aggregate (9 feats; xs premultiplied in gather2), fused transform
  k_agg9  <<<(N*9+255)/256, 256, 0, stream>>>(xs, dis, row_ptr, csr, xagg, N);
  k_lin1_fused<<<AGG_BLOCKS, 256, 0, stream>>>(xagg, W1, b1, dis, W2, mA, N, AGG_WAVES);

  // layer 2: aggregate m2 -> h2 (regs) -> m3   (uses b2, W3)
  k_agg_fused<<<AGG_BLOCKS, 256, 0, stream>>>((const h8v*)mA, dis, b2, W3,
                                              row_ptr, csr, mB, N, AGG_WAVES);
  // layer 3: aggregate m3 -> h3 (regs) -> m4   (uses b3, W4)
  k_agg_fused<<<AGG_BLOCKS, 256, 0, stream>>>((const h8v*)mB, dis, b3, W4,
                                              row_ptr, csr, mA, N, AGG_WAVES);
  // layer 4: aggregate m4 -> h4 (regs) -> Wout dot -> pooled sums
  k_agg64_out<<<AGG_BLOCKS, 256, 0, stream>>>((const h8v*)mA, dis, b4, Wout, batch,
                                              row_ptr, csr, gsum, N, AGG_WAVES);

  k_final<<<(G+255)/256, 256, 0, stream>>>(gsum, batch, bout, out, G, N);
}

// Round 15
// 299.731 us; speedup vs baseline: 1.2671x; 1.0073x over previous
//
#include <hip/hip_runtime.h>
#include <hip/hip_fp16.h>

// GCN: 4x (gcn_conv + relu) + global mean pool + linear out.
// N=100000 nodes, E=1000000 edges, G=4096 graphs, F_IN=9, H=64.
// R1-R8: gather MLP restructure, scatter-free CSR, fp16 rows, MFMA-fused
//     transform in agg epilogue (h never stored).  379us.
// R9-R12: pipeline agg_fused (65->47, keep); agg64_out pipelining REGRESSED
//     (60->70).  Selective revert: 341us.
// R13-R15: deg-free graph build; bktsum block-per-bucket: 308us.
// R16: gather2 LDS staging + kernel folds (-8us rest) BUT agg64_out rotate
//     pipeline regressed AGAIN (59.5->61.4, occupancy 65->34%): carrying 2x
//     48B gather register sets across iterations collapses occupancy.
// R17: (1) agg64_out INDEX-AHEAD pipeline: R8 while-loop + prefetch of next
//     node's csr INDICES only (2 ints; no gather regs carried) -- removes the
//     ~200cy csr->gather link without the R11/R16 failure mechanism.
//     (2) CHUNK 2048->4096: halves sortchunk's per-block-scan total, hoffC
//     traffic, and gather2 segment count.  (3) bktscan folded into gather2
//     (per-block btot prefix reduce).  10 -> 9 kernels.

static inline size_t align256(size_t x){ return (x + 255) & ~size_t(255); }

#define CHUNK 4096          // edges per sort chunk (16KB LDS image)
#define SCAP  3072          // gather2 LDS edge-staging capacity (12KB)

struct __align__(8)  h4v { __half2 a, b; };        // 4 halves = 8B
struct __align__(16) h8v { __half2 a, b, c, d; };  // 8 halves = 16B (agg gather)

typedef _Float16 f16x8 __attribute__((ext_vector_type(8)));
typedef float    f32x4 __attribute__((ext_vector_type(4)));

// pass 1: sort a 4096-edge chunk by bucket entirely in LDS, emit the sorted
// image (coalesced) + the chunk's 783-entry bucket-offset row (coalesced).
// Entry packed as (src<<7)|(dst&127); src < 2^17 fits.  Two 8-edge register
// batches (static-indexed; one 16-array would be fine too but this caps VGPR).
__global__ __launch_bounds__(256) void k_sortchunk(
    const int* __restrict__ src, const int* __restrict__ dst,
    int* __restrict__ binned, int* __restrict__ hoffC, int E){
  __shared__ int hcnt[1024];            // 782 used; padded pow2 for scan
  __shared__ int simg[CHUNK];
  int c = blockIdx.x, t = threadIdx.x;
  int e0 = c*CHUNK;
  int cnt = E - e0; if (cnt > CHUNK) cnt = CHUNK;

  for (int i = t; i < 1024; i += 256) hcnt[i] = 0;
  __syncthreads();

  int bA[8], rA[8], vA[8], bB[8], rB[8], vB[8];
  #pragma unroll
  for (int j = 0; j < 8; j++){
    int i = t + j*256;
    if (i < cnt){
      int d = dst[e0+i];
      int s = src[e0+i];
      int b = d >> 7;
      bA[j] = b;
      rA[j] = atomicAdd(&hcnt[b], 1);
      vA[j] = (s << 7) | (d & 127);
    } else bA[j] = -1;
  }
  #pragma unroll
  for (int j = 0; j < 8; j++){
    int i = t + 2048 + j*256;
    if (i < cnt){
      int d = dst[e0+i];
      int s = src[e0+i];
      int b = d >> 7;
      bB[j] = b;
      rB[j] = atomicAdd(&hcnt[b], 1);
      vB[j] = (s << 7) | (d & 127);
    } else bB[j] = -1;
  }
  __syncthreads();

  // in-place Hillis-Steele inclusive scan of hcnt[0..1023]
  int own[4];
  #pragma unroll
  for (int j = 0; j < 4; j++) own[j] = hcnt[t + j*256];
  for (int off = 1; off < 1024; off <<= 1){
    int nv[4];
    #pragma unroll
    for (int j = 0; j < 4; j++){
      int i = t + j*256;
      nv[j] = hcnt[i] + ((i >= off) ? hcnt[i-off] : 0);
    }
    __syncthreads();
    #pragma unroll
    for (int j = 0; j < 4; j++) hcnt[t + j*256] = nv[j];
    __syncthreads();
  }
  // inclusive -> exclusive
  #pragma unroll
  for (int j = 0; j < 4; j++) hcnt[t + j*256] -= own[j];
  __syncthreads();

  // emit bucket-offset row (hcnt[782] == cnt since buckets >=782 are empty)
  for (int i = t; i < 783; i += 256) hoffC[c*783 + i] = hcnt[i];

  // place edges bucket-major in LDS
  #pragma unroll
  for (int j = 0; j < 8; j++)
    if (bA[j] >= 0) simg[hcnt[bA[j]] + rA[j]] = vA[j];
  #pragma unroll
  for (int j = 0; j < 8; j++)
    if (bB[j] >= 0) simg[hcnt[bB[j]] + rB[j]] = vB[j];
  __syncthreads();

  // coalesced stream-out of the sorted chunk image
  for (int i = t; i < cnt; i += 256) binned[e0 + i] = simg[i];
}

// bucket totals: one block PER bucket; 256 threads stride the chunks and
// tree-reduce in LDS.  Also zeroes gsum (grid covers G easily).
__global__ __launch_bounds__(256) void k_bktsum(
    const int* __restrict__ hoffC, int* __restrict__ btot,
    float* __restrict__ gsum, int NC, int NBK, int G){
  __shared__ int s[256];
  int b = blockIdx.x, t = threadIdx.x;
  int gid = b*256 + t;
  if (gid < G) gsum[gid] = 0.f;
  int tot = 0;
  for (int c = t; c < NC; c += 256)
    tot += hoffC[c*783 + b + 1] - hoffC[c*783 + b];
  s[t] = tot; __syncthreads();
  for (int off = 128; off > 0; off >>= 1){
    if (t < off) s[t] += s[t+off];
    __syncthreads();
  }
  if (t == 0) btot[b] = s[0];
}

// pass 2: WG per bucket, single global pass over the bucket's segments.
//   prologue: bucket base = reduce(btot[0..b-1]) (L2-hot, stage[] as scratch)
//   pass A: stage edges into LDS (per-segment scount base) + count degrees
//   scan -> row_ptr, dis, cursors; fused premul writes xs = x*dis
//   pass B: place from LDS staging (global-rewalk fallback if overflow).
__global__ __launch_bounds__(256) void k_gather2(
    const int* __restrict__ binned, const int* __restrict__ hoffC,
    const int* __restrict__ btot, const float* __restrict__ x,
    int* __restrict__ row_ptr, float* __restrict__ dis,
    float* __restrict__ xs, int* __restrict__ csr, int N, int NC, int E){
  __shared__ int lcur[128];
  __shared__ int lscan[128];
  __shared__ float ldis[128];
  __shared__ int stage[SCAP];
  __shared__ int scount;
  __shared__ int sbb;
  int b = blockIdx.x, t = threadIdx.x;
  int n0 = b << 7;
  int nn = N - n0; if (nn > 128) nn = 128;

  // bucket base: exclusive prefix of btot up to b (parallel reduce)
  int psum = 0;
  for (int i = t; i < b; i += 256) psum += btot[i];
  stage[t] = psum; __syncthreads();
  for (int off = 128; off > 0; off >>= 1){
    if (t < off) stage[t] += stage[t+off];
    __syncthreads();
  }
  if (t == 0) sbb = stage[0];
  if (t == 0 && b == 0) row_ptr[N] = E;     // sentinel
  if (t < 128) lcur[t] = 0;
  if (t == 0) scount = 0;
  __syncthreads();

  // pass A: stage + degree count
  for (int c = t; c < NC; c += 256){
    int o0 = hoffC[c*783 + b];
    int o1 = hoffC[c*783 + b + 1];
    int len = o1 - o0;
    if (len > 0){
      int base = atomicAdd(&scount, len);
      int sbase = c*CHUNK;
      for (int k = 0; k < len; k++){
        int v = binned[sbase + o0 + k];
        atomicAdd(&lcur[v & 127], 1);
        int pos = base + k;
        if (pos < SCAP) stage[pos] = v;
      }
    }
  }
  __syncthreads();
  int degv = (t < 128) ? lcur[t] : 0;
  if (t < 128) lscan[t] = degv;
  __syncthreads();
  for (int off = 1; off < 128; off <<= 1){
    int add = (t < 128 && t >= off) ? lscan[t-off] : 0;
    __syncthreads();
    if (t < 128) lscan[t] += add;
    __syncthreads();
  }
  int bb = sbb;
  if (t < nn){
    int row = bb + lscan[t] - degv;        // exclusive
    row_ptr[n0 + t] = row;
    float dv = rsqrtf((float)(degv + 1));  // +1 self-loop
    dis[n0 + t] = dv;
    ldis[t] = dv;
    lcur[t] = row;                          // cursor for pass B
  }
  __syncthreads();
  // fused premul: xs = x * dis for this block's nodes (coalesced)
  for (int i = t; i < nn*9; i += 256)
    xs[(size_t)n0*9 + i] = x[(size_t)n0*9 + i] * ldis[i/9];
  // pass B: place
  int sc = scount;
  if (sc <= SCAP){
    for (int i = t; i < sc; i += 256){
      int v = stage[i];
      int pos = atomicAdd(&lcur[v & 127], 1);
      csr[pos] = v >> 7;
    }
  } else {
    // overflow fallback (statistically impossible: SCAP ~ 50 sigma): rewalk
    for (int c = t; c < NC; c += 256){
      int o0 = hoffC[c*783 + b];
      int o1 = hoffC[c*783 + b + 1];
      int sbase = c*CHUNK;
      for (int k = o0; k < o1; k++){
        int v = binned[sbase + k];
        int pos = atomicAdd(&lcur[v & 127], 1);
        csr[pos] = v >> 7;
      }
    }
  }
}

// layer-1 aggregation over xs (9 features): thread per (node, feature), unroll-4 MLP
__global__ void k_agg9(const float* __restrict__ xs, const float* __restrict__ dis,
                       const int* __restrict__ row_ptr, const int* __restrict__ csr,
                       float* __restrict__ xagg, int N){
  int tid = blockIdx.x*blockDim.x + threadIdx.x;
  if (tid >= N*9) return;
  int n = tid/9, f = tid - n*9;
  float dn = dis[n];
  int s0 = row_ptr[n], s1 = row_ptr[n+1];
  float a0 = xs[tid];                 // self-loop term (x[n]*dis[n])
  float a1 = 0.f, a2 = 0.f, a3 = 0.f;
  int j = s0;
  for (; j + 3 < s1; j += 4){
    int e0 = csr[j], e1 = csr[j+1], e2 = csr[j+2], e3 = csr[j+3];
    a0 += xs[e0*9+f];
    a1 += xs[e1*9+f];
    a2 += xs[e2*9+f];
    a3 += xs[e3*9+f];
  }
  for (; j < s1; j++) a0 += xs[csr[j]*9+f];
  xagg[tid] = ((a0+a1)+(a2+a3))*dn;
}

// MFMA epilogue shared by the fused kernels.  hlw = this wave's 16x72-half
// LDS tile (row i = node wid + i*nwaves, cols 0..63 = dis*h fp16, 64..71 pad).
__device__ __forceinline__ void mfma_epilogue(
    const _Float16* hlw, const f16x8 (&wf)[4][2],
    __half* __restrict__ mo, int wid, int nwaves, int N, int lane){
  int lm = lane & 15, lk = lane >> 4;
  f16x8 hb0 = *(const f16x8*)(hlw + lm*72 + lk*8);
  f16x8 hb1 = *(const f16x8*)(hlw + lm*72 + 32 + lk*8);
  int node = wid + lm*nwaves;
  bool ok = (node < N);
  __half* row = mo + (size_t)node*64;
  #pragma unroll
  for (int ft = 0; ft < 4; ft++){
    f32x4 acc = {0.f, 0.f, 0.f, 0.f};
    acc = __builtin_amdgcn_mfma_f32_16x16x32_f16(wf[ft][0], hb0, acc, 0, 0, 0);
    acc = __builtin_amdgcn_mfma_f32_16x16x32_f16(wf[ft][1], hb1, acc, 0, 0, 0);
    if (ok){
      h4v o;
      o.a = __floats2half2_rn(acc[0], acc[1]);
      o.b = __floats2half2_rn(acc[2], acc[3]);
      *(h4v*)(row + ft*16 + lk*4) = o;
    }
  }
}

#define LOAD_WFRAGS(Wn)                                                    \
  f16x8 wf[4][2];                                                          \
  { int lm_ = lane & 15, lk_ = lane >> 4;                                  \
    _Pragma("unroll") for (int ft = 0; ft < 4; ft++)                       \
    _Pragma("unroll") for (int kb = 0; kb < 2; kb++)                       \
    _Pragma("unroll") for (int j = 0; j < 8; j++)                          \
      wf[ft][kb][j] = (_Float16)Wn[(kb*32 + lk_*8 + j)*64 + ft*16 + lm_]; }

// layer 1 transform fused with next-layer message build:
// h1 = relu(xagg@W1+b1); m2 = fp16((dis*h1) @ W2).  h1 never stored.
__global__ __launch_bounds__(256) void k_lin1_fused(
    const float* __restrict__ xagg, const float* __restrict__ W1,
    const float* __restrict__ b1, const float* __restrict__ dis,
    const float* __restrict__ W2, __half* __restrict__ mo, int N, int nwaves){
  __shared__ float W1l[576];
  __shared__ float b1l[64];
  __shared__ _Float16 hl[4][16*72];
  int t = threadIdx.x;
  for (int i = t; i < 576; i += 256) W1l[i] = W1[i];
  if (t < 64) b1l[t] = b1[t];
  __syncthreads();
  int lane = t & 63, w = t >> 6;
  int wid = (blockIdx.x*blockDim.x + t) >> 6;
  LOAD_WFRAGS(W2)
  _Float16* hlw = hl[w];
  for (int i = 0; i < 16; i++){
    int n = wid + i*nwaves;
    _Float16 hv = (_Float16)0.f;
    if (n < N){
      float acc = b1l[lane];
      #pragma unroll
      for (int k = 0; k < 9; k++) acc = fmaf(xagg[n*9+k], W1l[k*64+lane], acc);
      hv = (_Float16)(fmaxf(acc, 0.f) * dis[n]);
    }
    hlw[i*72 + lane] = hv;
  }
  mfma_epilogue(hlw, wf, mo, wid, nwaves, N, lane);
}

// NOTE: param is g_ (NOT `a`): body reads members .a/.b/.c/.d and the
// preprocessor would substitute a same-named parameter into member tokens.
#define ACC8(g_)  do{ float2 t_;                                   \
  t_ = __half22float2((g_).a); acc0 += t_.x; acc1 += t_.y;         \
  t_ = __half22float2((g_).b); acc2 += t_.x; acc3 += t_.y;         \
  t_ = __half22float2((g_).c); acc4 += t_.x; acc5 += t_.y;         \
  t_ = __half22float2((g_).d); acc6 += t_.x; acc7 += t_.y; }while(0)

#define RED3(v)  do{ v += __shfl_xor(v, 8,64);                     \
                     v += __shfl_xor(v,16,64);                     \
                     v += __shfl_xor(v,32,64); }while(0)

// --- agg_fused pipeline stages (named register sets) ---
#define AGG_ISSUE(n_, rp0_, rp1_, rn0_, rn1_, e0_, e1_, g0_, g1_, sf_, dn_) \
  do{                                                                      \
    int nn_ = (n_) + 2*nwaves;                                             \
    rn0_ = 0; rn1_ = 0;                                                    \
    if (nn_ < N){ rn0_ = row_ptr[nn_]; rn1_ = row_ptr[nn_+1]; }            \
    e0_ = -1; e1_ = -1;                                                    \
    if ((n_) < N){                                                         \
      sf_ = m[(size_t)(n_)*8 + q2];                                        \
      dn_ = dis[n_];                                                       \
      int j0_ = (rp0_) + sub, j1_ = (rp0_) + 8 + sub;                      \
      if (j0_ < (rp1_)) e0_ = csr[j0_];                                    \
      if (j1_ < (rp1_)) e1_ = csr[j1_];                                    \
      if (e0_ >= 0) g0_ = m[(size_t)e0_*8 + q2];                           \
      if (e1_ >= 0) g1_ = m[(size_t)e1_*8 + q2];                           \
    }                                                                      \
  }while(0)

#define AGG_ACCRED(n_, rp0_, rp1_, e0_, e1_, g0_, g1_, sf_, dn_)           \
      float acc0=0.f,acc1=0.f,acc2=0.f,acc3=0.f;                           \
      float acc4=0.f,acc5=0.f,acc6=0.f,acc7=0.f;                           \
      if (e0_ >= 0) ACC8(g0_);                                             \
      if (e1_ >= 0) ACC8(g1_);                                             \
      for (int j_ = (rp0_) + 16 + sub; j_ < (rp1_); j_ += 8){              \
        h8v gx_ = m[(size_t)csr[j_]*8 + q2]; ACC8(gx_);                    \
      }                                                                    \
      RED3(acc0); RED3(acc1); RED3(acc2); RED3(acc3);                      \
      RED3(acc4); RED3(acc5); RED3(acc6); RED3(acc7);                      \
      float2 s01=__half22float2((sf_).a), s23=__half22float2((sf_).b);     \
      float2 s45=__half22float2((sf_).c), s67=__half22float2((sf_).d);     \
      float r0 = fmaxf(fmaf(acc0 + s01.x, dn_, bb0.x), 0.f);               \
      float r1 = fmaxf(fmaf(acc1 + s01.y, dn_, bb0.y), 0.f);               \
      float r2 = fmaxf(fmaf(acc2 + s23.x, dn_, bb0.z), 0.f);               \
      float r3 = fmaxf(fmaf(acc3 + s23.y, dn_, bb0.w), 0.f);               \
      float r4 = fmaxf(fmaf(acc4 + s45.x, dn_, bb1.x), 0.f);               \
      float r5 = fmaxf(fmaf(acc5 + s45.y, dn_, bb1.y), 0.f);               \
      float r6 = fmaxf(fmaf(acc6 + s67.x, dn_, bb1.z), 0.f);               \
      float r7 = fmaxf(fmaf(acc7 + s67.y, dn_, bb1.w), 0.f);

#define AGG_REDUCE(n_, rp0_, rp1_, e0_, e1_, g0_, g1_, sf_, dn_, i_)       \
  do{                                                                      \
    if ((n_) < N){                                                         \
      AGG_ACCRED(n_, rp0_, rp1_, e0_, e1_, g0_, g1_, sf_, dn_)             \
      if (sub == 0){                                                       \
        h8v hv_;                                                           \
        hv_.a = __floats2half2_rn(r0*(dn_), r1*(dn_));                     \
        hv_.b = __floats2half2_rn(r2*(dn_), r3*(dn_));                     \
        hv_.c = __floats2half2_rn(r4*(dn_), r5*(dn_));                     \
        hv_.d = __floats2half2_rn(r6*(dn_), r7*(dn_));                     \
        *(h8v*)(hlw + (i_)*72 + q2*8) = hv_;                               \
      }                                                                    \
    } else if (sub == 0){                                                  \
      h8v z_; z_.a = __floats2half2_rn(0.f, 0.f);                          \
      z_.b = z_.a; z_.c = z_.a; z_.d = z_.a;                               \
      *(h8v*)(hlw + (i_)*72 + q2*8) = z_;                                  \
    }                                                                      \
  }while(0)

// layers 2,3: pipelined gather + fused next-layer transform.
__global__ __launch_bounds__(256) void k_agg_fused(
    const h8v* __restrict__ m, const float* __restrict__ dis,
    const float* __restrict__ b, const float* __restrict__ Wn,
    const int* __restrict__ row_ptr, const int* __restrict__ csr,
    __half* __restrict__ mo, int N, int nwaves){
  __shared__ _Float16 hl[4][16*72];
  int t = threadIdx.x;
  int lane = t & 63, w = t >> 6;
  int sub = lane >> 3, q2 = lane & 7;
  int wid = (blockIdx.x*blockDim.x + t) >> 6;
  _Float16* hlw = hl[w];
  const float4* b4 = (const float4*)b;
  float4 bb0 = b4[q2*2], bb1 = b4[q2*2+1];

  int nA = wid,          rA0 = 0, rA1 = 0;
  int nB = wid + nwaves, rB0 = 0, rB1 = 0;
  if (nA < N){ rA0 = row_ptr[nA]; rA1 = row_ptr[nA+1]; }
  if (nB < N){ rB0 = row_ptr[nB]; rB1 = row_ptr[nB+1]; }
  int eA0, eA1, eB0, eB1, rnA0, rnA1, rnB0, rnB1;
  h8v gA0, gA1, sfA, gB0, gB1, sfB;
  float dnA = 0.f, dnB = 0.f;
  AGG_ISSUE(nA, rA0, rA1, rnA0, rnA1, eA0, eA1, gA0, gA1, sfA, dnA);
  for (int p = 0; p < 8; p++){
    AGG_ISSUE(nB, rB0, rB1, rnB0, rnB1, eB0, eB1, gB0, gB1, sfB, dnB);
    AGG_REDUCE(nA, rA0, rA1, eA0, eA1, gA0, gA1, sfA, dnA, 2*p);
    nA += 2*nwaves; rA0 = rnA0; rA1 = rnA1;
    if (p < 7)
      AGG_ISSUE(nA, rA0, rA1, rnA0, rnA1, eA0, eA1, gA0, gA1, sfA, dnA);
    AGG_REDUCE(nB, rB0, rB1, eB0, eB1, gB0, gB1, sfB, dnB, 2*p+1);
    nB += 2*nwaves; rB0 = rnB0; rB1 = rnB1;
  }
  LOAD_WFRAGS(Wn)            // loaded at epilogue: not live during main loop
  mfma_epilogue(hlw, wf, mo, wid, nwaves, N, lane);
}

// layer 4: R8 while-loop + INDEX-AHEAD prefetch: during iter i's reduce, the
// csr indices for i+1 (2 ints) and row_ptr for i+2 are in flight.  No gather
// registers carried across iterations (the R11/R16 occupancy-collapse cause).
__global__ __launch_bounds__(256) void k_agg64_out(
    const h8v* __restrict__ m, const float* __restrict__ dis,
    const float* __restrict__ b, const float* __restrict__ Wout,
    const int* __restrict__ batch,
    const int* __restrict__ row_ptr, const int* __restrict__ csr,
    float* gsum, int N, int nwaves){
  int lane = threadIdx.x & 63;
  int sub = lane >> 3, q2 = lane & 7;
  int n = (blockIdx.x*blockDim.x + threadIdx.x) >> 6;
  if (n >= N) return;
  const float4* b4 = (const float4*)b;
  const float4* wo4 = (const float4*)Wout;
  float4 bb0 = b4[q2*2], bb1 = b4[q2*2+1];
  float4 w0 = wo4[q2*2], w1 = wo4[q2*2+1];

  int rp0 = row_ptr[n], rp1 = row_ptr[n+1];
  int n1 = n + nwaves;
  int rq0 = 0, rq1 = 0;
  if (n1 < N){ rq0 = row_ptr[n1]; rq1 = row_ptr[n1+1]; }
  int e0 = -1, e1 = -1;
  { int j0 = rp0 + sub, j1 = rp0 + 8 + sub;
    if (j0 < rp1) e0 = csr[j0];
    if (j1 < rp1) e1 = csr[j1]; }
  while (true){
    // issue this node's gathers + self/dis/batch (independent loads)
    h8v g0, g1, sf;
    if (e0 >= 0) g0 = m[(size_t)e0*8 + q2];
    if (e1 >= 0) g1 = m[(size_t)e1*8 + q2];
    sf = m[(size_t)n*8 + q2];
    float dn = dis[n];
    int bg = batch[n];
    // index-ahead: row_ptr for n+2*nwaves, csr indices for n+nwaves
    int n2 = n1 + nwaves;
    int rr0 = 0, rr1 = 0;
    if (n2 < N){ rr0 = row_ptr[n2]; rr1 = row_ptr[n2+1]; }
    int f0 = -1, f1 = -1;
    if (n1 < N){
      int j0 = rq0 + sub, j1 = rq0 + 8 + sub;
      if (j0 < rq1) f0 = csr[j0];
      if (j1 < rq1) f1 = csr[j1];
    }
    // reduce
    AGG_ACCRED(n, rp0, rp1, e0, e1, g0, g1, sf, dn)
    float p = r0*w0.x + r1*w0.y + r2*w0.z + r3*w0.w
            + r4*w1.x + r5*w1.y + r6*w1.z + r7*w1.w;
    p += __shfl_xor(p,1,64); p += __shfl_xor(p,2,64); p += __shfl_xor(p,4,64);
    if (lane == 0) atomicAdd(&gsum[bg], p);
    if (n1 >= N) break;
    n = n1; rp0 = rq0; rp1 = rq1;
    n1 = n2; rq0 = rr0; rq1 = rr1;
    e0 = f0; e1 = f1;
  }
}

// final: per-graph count via binary search on SORTED batch (no atomics),
// then mean + bias.
__global__ void k_final(const float* __restrict__ gsum, const int* __restrict__ batch,
                        const float* __restrict__ bout, float* __restrict__ out,
                        int G, int N){
  int g = blockIdx.x*blockDim.x + threadIdx.x;
  if (g >= G) return;
  int lo = 0, hi = N;
  while (lo < hi){ int mid = (lo+hi)>>1; if (batch[mid] <  g) lo = mid+1; else hi = mid; }
  int lb = lo;
  lo = 0; hi = N;
  while (lo < hi){ int mid = (lo+hi)>>1; if (batch[mid] <= g) lo = mid+1; else hi = mid; }
  int c = lo - lb;
  out[g] = gsum[g]/(float)(c > 0 ? c : 1) + bout[0];
}

extern "C" void kernel_launch(void* const* d_in, const int* in_sizes, int n_in,
                              void* d_out, int out_size, void* d_ws, size_t ws_size,
                              hipStream_t stream){
  const float* x    = (const float*)d_in[0];
  const int*   ei   = (const int*)d_in[1];
  const int*   batch= (const int*)d_in[2];
  const float* W1 = (const float*)d_in[3];  const float* b1 = (const float*)d_in[4];
  const float* W2 = (const float*)d_in[5];  const float* b2 = (const float*)d_in[6];
  const float* W3 = (const float*)d_in[7];  const float* b3 = (const float*)d_in[8];
  const float* W4 = (const float*)d_in[9];  const float* b4 = (const float*)d_in[10];
  const float* Wout = (const float*)d_in[11]; const float* bout = (const float*)d_in[12];
  float* out = (float*)d_out;

  const int N = in_sizes[0]/9;
  const int E = in_sizes[1]/2;
  const int G = out_size;
  const int* src = ei;        // edge_index[0]
  const int* dst = ei + E;    // edge_index[1]

  char* ws = (char*)d_ws;
  size_t off = 0;
  auto alloc = [&](size_t bytes){ void* p = ws + off; off = align256(off + bytes); return p; };
  int*   row_ptr  = (int*)  alloc((size_t)(N+1)*4);
  int*   csr      = (int*)  alloc((size_t)E*4);
  float* dis      = (float*)alloc((size_t)N*4);
  const int NBK = (N + 127)/128;        // 782 buckets of 128 dst nodes
  const int NC  = (E + CHUNK-1)/CHUNK;  // 245 sort chunks
  int*   hoffC    = (int*)  alloc((size_t)NC*783*4);   // per-chunk bucket offsets
  int*   btot     = (int*)  alloc((size_t)NBK*4);
  float* gsum     = (float*)alloc((size_t)G*4);
  __half* mA      = (__half*)alloc((size_t)N*64*2);  // fp16 message ping
  __half* mB      = (__half*)alloc((size_t)N*64*2);  // fp16 message pong
  // aliases (lifetimes verified):
  int*   binned   = (int*)mA;              // 4MB <= 12.8MB; dead after k_gather2
  float* xs       = (float*)mB;            // 3.6MB; written by gather2, dead after agg9
  float* xagg     = xs + (size_t)N*9;      // 3.6MB; dead after k_lin1_fused
  // m2 = mA (written by lin1_fused, after binned dead)
  // m3 = mB (written by aggF layer2, after xs/xagg dead)
  // m4 = mA (written by aggF layer3, after m2 dead)

  const int AGG_BLOCKS = 2048;             // persistent: 8 blocks/CU on 256 CUs
  const int AGG_WAVES  = AGG_BLOCKS*4;     // 8192 waves; 16*8192 >= N (batch=16)

  k_sortchunk<<<NC, 256, 0, stream>>>(src, dst, binned, hoffC, E);
  k_bktsum   <<<NBK, 256, 0, stream>>>(hoffC, btot, gsum, NC, NBK, G);
  k_gather2  <<<NBK, 256, 0, stream>>>(binned, hoffC, btot, x,
                                       row_ptr, dis, xs, csr, N, NC, E);

  // layer 1: aggregate (9 feats; xs premultiplied in gather2), fused transform
  k_agg9  <<<(N*9+255)/256, 256, 0, stream>>>(xs, dis, row_ptr, csr, xagg, N);
  k_lin1_fused<<<AGG_BLOCKS, 256, 0, stream>>>(xagg, W1, b1, dis, W2, mA, N, AGG_WAVES);

  // layer 2: aggregate m2 -> h2 (regs) -> m3   (uses b2, W3)
  k_agg_fused<<<AGG_BLOCKS, 256, 0, stream>>>((const h8v*)mA, dis, b2, W3,
                                              row_ptr, csr, mB, N, AGG_WAVES);
  // layer 3: aggregate m3 -> h3 (regs) -> m4   (uses b3, W4)
  k_agg_fused<<<AGG_BLOCKS, 256, 0, stream>>>((const h8v*)mB, dis, b3, W4,
                                              row_ptr, csr, mA, N, AGG_WAVES);
  // layer 4: aggregate m4 -> h4 (regs) -> Wout dot -> pooled sums
  k_agg64_out<<<AGG_BLOCKS, 256, 0, stream>>>((const h8v*)mA, dis, b4, Wout, batch,
                                              row_ptr, csr, gsum, N, AGG_WAVES);

  k_final<<<(G+255)/256, 256, 0, stream>>>(gsum, batch, bout, out, G, N);
}

// Round 16
// 297.355 us; speedup vs baseline: 1.2772x; 1.0080x over previous
//
#include <hip/hip_runtime.h>
#include <hip/hip_fp16.h>

// GCN: 4x (gcn_conv + relu) + global mean pool + linear out.
// N=100000 nodes, E=1000000 edges, G=4096 graphs, F_IN=9, H=64.
// R1-R8: gather MLP restructure, scatter-free CSR, fp16 rows, MFMA-fused
//     transform in agg epilogue (h never stored).  379us.
// R9-R12: pipeline agg_fused (65->47, keep); agg64_out pipelining regressed.
// R13-R15: deg-free graph build; bktsum block-per-bucket: 308us.
// R16/R17: gather2 LDS staging, CHUNK=4096, bktscan fold: 299.7us.  agg64_out
//     pipelining regressed a THIRD time (61 vs 59.5; index-ahead variant) --
//     R8's while-loop already issues 17 independent loads/iter; ANY carried
//     state costs more occupancy than the hidden csr latency.  CLOSED.
// R18: (1) permanent R8 revert of agg64_out.  (2) k_agg9 width fix: was 9M
//     scattered 4B loads (thread per node-FEATURE, 9 threads re-resolving the
//     same edge); now thread-per-node over 48B padded rows (xs padded to 12
//     floats in gather2; 3 aligned float4 loads/edge, unroll-2).  9M -> 3M
//     requests, 4x wider.  xagg padded to 12 (aligned f4 stores).

static inline size_t align256(size_t x){ return (x + 255) & ~size_t(255); }

#define CHUNK 4096          // edges per sort chunk (16KB LDS image)
#define SCAP  3072          // gather2 LDS edge-staging capacity (12KB)

struct __align__(8)  h4v { __half2 a, b; };        // 4 halves = 8B
struct __align__(16) h8v { __half2 a, b, c, d; };  // 8 halves = 16B (agg gather)

typedef _Float16 f16x8 __attribute__((ext_vector_type(8)));
typedef float    f32x4 __attribute__((ext_vector_type(4)));

// pass 1: sort a 4096-edge chunk by bucket entirely in LDS, emit the sorted
// image (coalesced) + the chunk's 783-entry bucket-offset row (coalesced).
// Entry packed as (src<<7)|(dst&127); src < 2^17 fits.
__global__ __launch_bounds__(256) void k_sortchunk(
    const int* __restrict__ src, const int* __restrict__ dst,
    int* __restrict__ binned, int* __restrict__ hoffC, int E){
  __shared__ int hcnt[1024];            // 782 used; padded pow2 for scan
  __shared__ int simg[CHUNK];
  int c = blockIdx.x, t = threadIdx.x;
  int e0 = c*CHUNK;
  int cnt = E - e0; if (cnt > CHUNK) cnt = CHUNK;

  for (int i = t; i < 1024; i += 256) hcnt[i] = 0;
  __syncthreads();

  int bA[8], rA[8], vA[8], bB[8], rB[8], vB[8];
  #pragma unroll
  for (int j = 0; j < 8; j++){
    int i = t + j*256;
    if (i < cnt){
      int d = dst[e0+i];
      int s = src[e0+i];
      int b = d >> 7;
      bA[j] = b;
      rA[j] = atomicAdd(&hcnt[b], 1);
      vA[j] = (s << 7) | (d & 127);
    } else bA[j] = -1;
  }
  #pragma unroll
  for (int j = 0; j < 8; j++){
    int i = t + 2048 + j*256;
    if (i < cnt){
      int d = dst[e0+i];
      int s = src[e0+i];
      int b = d >> 7;
      bB[j] = b;
      rB[j] = atomicAdd(&hcnt[b], 1);
      vB[j] = (s << 7) | (d & 127);
    } else bB[j] = -1;
  }
  __syncthreads();

  // in-place Hillis-Steele inclusive scan of hcnt[0..1023]
  int own[4];
  #pragma unroll
  for (int j = 0; j < 4; j++) own[j] = hcnt[t + j*256];
  for (int off = 1; off < 1024; off <<= 1){
    int nv[4];
    #pragma unroll
    for (int j = 0; j < 4; j++){
      int i = t + j*256;
      nv[j] = hcnt[i] + ((i >= off) ? hcnt[i-off] : 0);
    }
    __syncthreads();
    #pragma unroll
    for (int j = 0; j < 4; j++) hcnt[t + j*256] = nv[j];
    __syncthreads();
  }
  // inclusive -> exclusive
  #pragma unroll
  for (int j = 0; j < 4; j++) hcnt[t + j*256] -= own[j];
  __syncthreads();

  // emit bucket-offset row (hcnt[782] == cnt since buckets >=782 are empty)
  for (int i = t; i < 783; i += 256) hoffC[c*783 + i] = hcnt[i];

  // place edges bucket-major in LDS
  #pragma unroll
  for (int j = 0; j < 8; j++)
    if (bA[j] >= 0) simg[hcnt[bA[j]] + rA[j]] = vA[j];
  #pragma unroll
  for (int j = 0; j < 8; j++)
    if (bB[j] >= 0) simg[hcnt[bB[j]] + rB[j]] = vB[j];
  __syncthreads();

  // coalesced stream-out of the sorted chunk image
  for (int i = t; i < cnt; i += 256) binned[e0 + i] = simg[i];
}

// bucket totals: one block PER bucket; 256 threads stride the chunks and
// tree-reduce in LDS.  Also zeroes gsum (grid covers G easily).
__global__ __launch_bounds__(256) void k_bktsum(
    const int* __restrict__ hoffC, int* __restrict__ btot,
    float* __restrict__ gsum, int NC, int NBK, int G){
  __shared__ int s[256];
  int b = blockIdx.x, t = threadIdx.x;
  int gid = b*256 + t;
  if (gid < G) gsum[gid] = 0.f;
  int tot = 0;
  for (int c = t; c < NC; c += 256)
    tot += hoffC[c*783 + b + 1] - hoffC[c*783 + b];
  s[t] = tot; __syncthreads();
  for (int off = 128; off > 0; off >>= 1){
    if (t < off) s[t] += s[t+off];
    __syncthreads();
  }
  if (t == 0) btot[b] = s[0];
}

// pass 2: WG per bucket, single global pass over the bucket's segments.
//   prologue: bucket base = reduce(btot[0..b-1]) (L2-hot, stage[] as scratch)
//   pass A: stage edges into LDS (per-segment scount base) + count degrees
//   scan -> row_ptr, dis, cursors; fused premul writes xs = x*dis (PADDED 12)
//   pass B: place from LDS staging (global-rewalk fallback if overflow).
__global__ __launch_bounds__(256) void k_gather2(
    const int* __restrict__ binned, const int* __restrict__ hoffC,
    const int* __restrict__ btot, const float* __restrict__ x,
    int* __restrict__ row_ptr, float* __restrict__ dis,
    float* __restrict__ xs, int* __restrict__ csr, int N, int NC, int E){
  __shared__ int lcur[128];
  __shared__ int lscan[128];
  __shared__ float ldis[128];
  __shared__ int stage[SCAP];
  __shared__ int scount;
  __shared__ int sbb;
  int b = blockIdx.x, t = threadIdx.x;
  int n0 = b << 7;
  int nn = N - n0; if (nn > 128) nn = 128;

  // bucket base: exclusive prefix of btot up to b (parallel reduce)
  int psum = 0;
  for (int i = t; i < b; i += 256) psum += btot[i];
  stage[t] = psum; __syncthreads();
  for (int off = 128; off > 0; off >>= 1){
    if (t < off) stage[t] += stage[t+off];
    __syncthreads();
  }
  if (t == 0) sbb = stage[0];
  if (t == 0 && b == 0) row_ptr[N] = E;     // sentinel
  if (t < 128) lcur[t] = 0;
  if (t == 0) scount = 0;
  __syncthreads();

  // pass A: stage + degree count
  for (int c = t; c < NC; c += 256){
    int o0 = hoffC[c*783 + b];
    int o1 = hoffC[c*783 + b + 1];
    int len = o1 - o0;
    if (len > 0){
      int base = atomicAdd(&scount, len);
      int sbase = c*CHUNK;
      for (int k = 0; k < len; k++){
        int v = binned[sbase + o0 + k];
        atomicAdd(&lcur[v & 127], 1);
        int pos = base + k;
        if (pos < SCAP) stage[pos] = v;
      }
    }
  }
  __syncthreads();
  int degv = (t < 128) ? lcur[t] : 0;
  if (t < 128) lscan[t] = degv;
  __syncthreads();
  for (int off = 1; off < 128; off <<= 1){
    int add = (t < 128 && t >= off) ? lscan[t-off] : 0;
    __syncthreads();
    if (t < 128) lscan[t] += add;
    __syncthreads();
  }
  int bb = sbb;
  if (t < nn){
    int row = bb + lscan[t] - degv;        // exclusive
    row_ptr[n0 + t] = row;
    float dv = rsqrtf((float)(degv + 1));  // +1 self-loop
    dis[n0 + t] = dv;
    ldis[t] = dv;
    lcur[t] = row;                          // cursor for pass B
  }
  __syncthreads();
  // fused premul: xs rows PADDED to 12 floats (48B, float4-aligned);
  // cols 9..11 are zero so the padded gather adds 0.
  for (int i = t; i < nn*12; i += 256){
    int node = i/12, f = i - node*12;
    xs[(size_t)(n0+node)*12 + f] =
        (f < 9) ? x[(size_t)(n0+node)*9 + f] * ldis[node] : 0.f;
  }
  // pass B: place
  int sc = scount;
  if (sc <= SCAP){
    for (int i = t; i < sc; i += 256){
      int v = stage[i];
      int pos = atomicAdd(&lcur[v & 127], 1);
      csr[pos] = v >> 7;
    }
  } else {
    // overflow fallback (statistically impossible: SCAP ~ 50 sigma): rewalk
    for (int c = t; c < NC; c += 256){
      int o0 = hoffC[c*783 + b];
      int o1 = hoffC[c*783 + b + 1];
      int sbase = c*CHUNK;
      for (int k = o0; k < o1; k++){
        int v = binned[sbase + k];
        int pos = atomicAdd(&lcur[v & 127], 1);
        csr[pos] = v >> 7;
      }
    }
  }
}

#define F4ADD(d_, s_) do{ d_.x += s_.x; d_.y += s_.y; d_.z += s_.z; d_.w += s_.w; }while(0)

// layer-1 aggregation: thread per NODE over 48B padded xs rows; 3 aligned
// float4 loads/edge, unroll-2 (6 loads in flight).  xagg padded to 12.
__global__ __launch_bounds__(256) void k_agg9(
    const float4* __restrict__ xs4, const float* __restrict__ dis,
    const int* __restrict__ row_ptr, const int* __restrict__ csr,
    float4* __restrict__ xagg4, int N){
  int n = blockIdx.x*blockDim.x + threadIdx.x;
  if (n >= N) return;
  float dn = dis[n];
  int s0 = row_ptr[n], s1 = row_ptr[n+1];
  float4 a0 = xs4[(size_t)n*3], a1 = xs4[(size_t)n*3+1], a2 = xs4[(size_t)n*3+2];
  float4 b0 = {0,0,0,0}, b1 = b0, b2 = b0;
  int j = s0;
  for (; j + 1 < s1; j += 2){
    int e0 = csr[j], e1 = csr[j+1];
    float4 p0 = xs4[(size_t)e0*3], p1 = xs4[(size_t)e0*3+1], p2 = xs4[(size_t)e0*3+2];
    float4 q0 = xs4[(size_t)e1*3], q1 = xs4[(size_t)e1*3+1], q2 = xs4[(size_t)e1*3+2];
    F4ADD(a0,p0); F4ADD(a1,p1); F4ADD(a2,p2);
    F4ADD(b0,q0); F4ADD(b1,q1); F4ADD(b2,q2);
  }
  if (j < s1){
    int e0 = csr[j];
    float4 p0 = xs4[(size_t)e0*3], p1 = xs4[(size_t)e0*3+1], p2 = xs4[(size_t)e0*3+2];
    F4ADD(a0,p0); F4ADD(a1,p1); F4ADD(a2,p2);
  }
  F4ADD(a0,b0); F4ADD(a1,b1); F4ADD(a2,b2);
  a0.x *= dn; a0.y *= dn; a0.z *= dn; a0.w *= dn;
  a1.x *= dn; a1.y *= dn; a1.z *= dn; a1.w *= dn;
  a2.x *= dn; a2.y *= dn; a2.z *= dn; a2.w *= dn;
  xagg4[(size_t)n*3]   = a0;
  xagg4[(size_t)n*3+1] = a1;
  xagg4[(size_t)n*3+2] = a2;
}

// MFMA epilogue shared by the fused kernels.  hlw = this wave's 16x72-half
// LDS tile (row i = node wid + i*nwaves, cols 0..63 = dis*h fp16, 64..71 pad).
__device__ __forceinline__ void mfma_epilogue(
    const _Float16* hlw, const f16x8 (&wf)[4][2],
    __half* __restrict__ mo, int wid, int nwaves, int N, int lane){
  int lm = lane & 15, lk = lane >> 4;
  f16x8 hb0 = *(const f16x8*)(hlw + lm*72 + lk*8);
  f16x8 hb1 = *(const f16x8*)(hlw + lm*72 + 32 + lk*8);
  int node = wid + lm*nwaves;
  bool ok = (node < N);
  __half* row = mo + (size_t)node*64;
  #pragma unroll
  for (int ft = 0; ft < 4; ft++){
    f32x4 acc = {0.f, 0.f, 0.f, 0.f};
    acc = __builtin_amdgcn_mfma_f32_16x16x32_f16(wf[ft][0], hb0, acc, 0, 0, 0);
    acc = __builtin_amdgcn_mfma_f32_16x16x32_f16(wf[ft][1], hb1, acc, 0, 0, 0);
    if (ok){
      h4v o;
      o.a = __floats2half2_rn(acc[0], acc[1]);
      o.b = __floats2half2_rn(acc[2], acc[3]);
      *(h4v*)(row + ft*16 + lk*4) = o;
    }
  }
}

#define LOAD_WFRAGS(Wn)                                                    \
  f16x8 wf[4][2];                                                          \
  { int lm_ = lane & 15, lk_ = lane >> 4;                                  \
    _Pragma("unroll") for (int ft = 0; ft < 4; ft++)                       \
    _Pragma("unroll") for (int kb = 0; kb < 2; kb++)                       \
    _Pragma("unroll") for (int j = 0; j < 8; j++)                          \
      wf[ft][kb][j] = (_Float16)Wn[(kb*32 + lk_*8 + j)*64 + ft*16 + lm_]; }

// layer 1 transform fused with next-layer message build:
// h1 = relu(xagg@W1+b1); m2 = fp16((dis*h1) @ W2).  h1 never stored.
// xagg rows are PADDED to 12 floats.
__global__ __launch_bounds__(256) void k_lin1_fused(
    const float* __restrict__ xagg, const float* __restrict__ W1,
    const float* __restrict__ b1, const float* __restrict__ dis,
    const float* __restrict__ W2, __half* __restrict__ mo, int N, int nwaves){
  __shared__ float W1l[576];
  __shared__ float b1l[64];
  __shared__ _Float16 hl[4][16*72];
  int t = threadIdx.x;
  for (int i = t; i < 576; i += 256) W1l[i] = W1[i];
  if (t < 64) b1l[t] = b1[t];
  __syncthreads();
  int lane = t & 63, w = t >> 6;
  int wid = (blockIdx.x*blockDim.x + t) >> 6;
  LOAD_WFRAGS(W2)
  _Float16* hlw = hl[w];
  for (int i = 0; i < 16; i++){
    int n = wid + i*nwaves;
    _Float16 hv = (_Float16)0.f;
    if (n < N){
      float acc = b1l[lane];
      #pragma unroll
      for (int k = 0; k < 9; k++) acc = fmaf(xagg[(size_t)n*12+k], W1l[k*64+lane], acc);
      hv = (_Float16)(fmaxf(acc, 0.f) * dis[n]);
    }
    hlw[i*72 + lane] = hv;
  }
  mfma_epilogue(hlw, wf, mo, wid, nwaves, N, lane);
}

// NOTE: param is g_ (NOT `a`): body reads members .a/.b/.c/.d and the
// preprocessor would substitute a same-named parameter into member tokens.
#define ACC8(g_)  do{ float2 t_;                                   \
  t_ = __half22float2((g_).a); acc0 += t_.x; acc1 += t_.y;         \
  t_ = __half22float2((g_).b); acc2 += t_.x; acc3 += t_.y;         \
  t_ = __half22float2((g_).c); acc4 += t_.x; acc5 += t_.y;         \
  t_ = __half22float2((g_).d); acc6 += t_.x; acc7 += t_.y; }while(0)

#define RED3(v)  do{ v += __shfl_xor(v, 8,64);                     \
                     v += __shfl_xor(v,16,64);                     \
                     v += __shfl_xor(v,32,64); }while(0)

// --- agg_fused pipeline stages (named register sets) ---
#define AGG_ISSUE(n_, rp0_, rp1_, rn0_, rn1_, e0_, e1_, g0_, g1_, sf_, dn_) \
  do{                                                                      \
    int nn_ = (n_) + 2*nwaves;                                             \
    rn0_ = 0; rn1_ = 0;                                                    \
    if (nn_ < N){ rn0_ = row_ptr[nn_]; rn1_ = row_ptr[nn_+1]; }            \
    e0_ = -1; e1_ = -1;                                                    \
    if ((n_) < N){                                                         \
      sf_ = m[(size_t)(n_)*8 + q2];                                        \
      dn_ = dis[n_];                                                       \
      int j0_ = (rp0_) + sub, j1_ = (rp0_) + 8 + sub;                      \
      if (j0_ < (rp1_)) e0_ = csr[j0_];                                    \
      if (j1_ < (rp1_)) e1_ = csr[j1_];                                    \
      if (e0_ >= 0) g0_ = m[(size_t)e0_*8 + q2];                           \
      if (e1_ >= 0) g1_ = m[(size_t)e1_*8 + q2];                           \
    }                                                                      \
  }while(0)

#define AGG_ACCRED(n_, rp0_, rp1_, e0_, e1_, g0_, g1_, sf_, dn_)           \
      float acc0=0.f,acc1=0.f,acc2=0.f,acc3=0.f;                           \
      float acc4=0.f,acc5=0.f,acc6=0.f,acc7=0.f;                           \
      if (e0_ >= 0) ACC8(g0_);                                             \
      if (e1_ >= 0) ACC8(g1_);                                             \
      for (int j_ = (rp0_) + 16 + sub; j_ < (rp1_); j_ += 8){              \
        h8v gx_ = m[(size_t)csr[j_]*8 + q2]; ACC8(gx_);                    \
      }                                                                    \
      RED3(acc0); RED3(acc1); RED3(acc2); RED3(acc3);                      \
      RED3(acc4); RED3(acc5); RED3(acc6); RED3(acc7);                      \
      float2 s01=__half22float2((sf_).a), s23=__half22float2((sf_).b);     \
      float2 s45=__half22float2((sf_).c), s67=__half22float2((sf_).d);     \
      float r0 = fmaxf(fmaf(acc0 + s01.x, dn_, bb0.x), 0.f);               \
      float r1 = fmaxf(fmaf(acc1 + s01.y, dn_, bb0.y), 0.f);               \
      float r2 = fmaxf(fmaf(acc2 + s23.x, dn_, bb0.z), 0.f);               \
      float r3 = fmaxf(fmaf(acc3 + s23.y, dn_, bb0.w), 0.f);               \
      float r4 = fmaxf(fmaf(acc4 + s45.x, dn_, bb1.x), 0.f);               \
      float r5 = fmaxf(fmaf(acc5 + s45.y, dn_, bb1.y), 0.f);               \
      float r6 = fmaxf(fmaf(acc6 + s67.x, dn_, bb1.z), 0.f);               \
      float r7 = fmaxf(fmaf(acc7 + s67.y, dn_, bb1.w), 0.f);

#define AGG_REDUCE(n_, rp0_, rp1_, e0_, e1_, g0_, g1_, sf_, dn_, i_)       \
  do{                                                                      \
    if ((n_) < N){                                                         \
      AGG_ACCRED(n_, rp0_, rp1_, e0_, e1_, g0_, g1_, sf_, dn_)             \
      if (sub == 0){                                                       \
        h8v hv_;                                                           \
        hv_.a = __floats2half2_rn(r0*(dn_), r1*(dn_));                     \
        hv_.b = __floats2half2_rn(r2*(dn_), r3*(dn_));                     \
        hv_.c = __floats2half2_rn(r4*(dn_), r5*(dn_));                     \
        hv_.d = __floats2half2_rn(r6*(dn_), r7*(dn_));                     \
        *(h8v*)(hlw + (i_)*72 + q2*8) = hv_;                               \
      }                                                                    \
    } else if (sub == 0){                                                  \
      h8v z_; z_.a = __floats2half2_rn(0.f, 0.f);                          \
      z_.b = z_.a; z_.c = z_.a; z_.d = z_.a;                               \
      *(h8v*)(hlw + (i_)*72 + q2*8) = z_;                                  \
    }                                                                      \
  }while(0)

// layers 2,3: pipelined gather + fused next-layer transform.
__global__ __launch_bounds__(256) void k_agg_fused(
    const h8v* __restrict__ m, const float* __restrict__ dis,
    const float* __restrict__ b, const float* __restrict__ Wn,
    const int* __restrict__ row_ptr, const int* __restrict__ csr,
    __half* __restrict__ mo, int N, int nwaves){
  __shared__ _Float16 hl[4][16*72];
  int t = threadIdx.x;
  int lane = t & 63, w = t >> 6;
  int sub = lane >> 3, q2 = lane & 7;
  int wid = (blockIdx.x*blockDim.x + t) >> 6;
  _Float16* hlw = hl[w];
  const float4* b4 = (const float4*)b;
  float4 bb0 = b4[q2*2], bb1 = b4[q2*2+1];

  int nA = wid,          rA0 = 0, rA1 = 0;
  int nB = wid + nwaves, rB0 = 0, rB1 = 0;
  if (nA < N){ rA0 = row_ptr[nA]; rA1 = row_ptr[nA+1]; }
  if (nB < N){ rB0 = row_ptr[nB]; rB1 = row_ptr[nB+1]; }
  int eA0, eA1, eB0, eB1, rnA0, rnA1, rnB0, rnB1;
  h8v gA0, gA1, sfA, gB0, gB1, sfB;
  float dnA = 0.f, dnB = 0.f;
  AGG_ISSUE(nA, rA0, rA1, rnA0, rnA1, eA0, eA1, gA0, gA1, sfA, dnA);
  for (int p = 0; p < 8; p++){
    AGG_ISSUE(nB, rB0, rB1, rnB0, rnB1, eB0, eB1, gB0, gB1, sfB, dnB);
    AGG_REDUCE(nA, rA0, rA1, eA0, eA1, gA0, gA1, sfA, dnA, 2*p);
    nA += 2*nwaves; rA0 = rnA0; rA1 = rnA1;
    if (p < 7)
      AGG_ISSUE(nA, rA0, rA1, rnA0, rnA1, eA0, eA1, gA0, gA1, sfA, dnA);
    AGG_REDUCE(nB, rB0, rB1, eB0, eB1, gB0, gB1, sfB, dnB, 2*p+1);
    nB += 2*nwaves; rB0 = rnB0; rB1 = rnB1;
  }
  LOAD_WFRAGS(Wn)            // loaded at epilogue: not live during main loop
  mfma_epilogue(hlw, wf, mo, wid, nwaves, N, lane);
}

// layer 4 (R8's measured-59.5us while-loop form, PERMANENT after 3 failed
// pipeline attempts): aggregation fused with output projection.
__global__ __launch_bounds__(256) void k_agg64_out(
    const h8v* __restrict__ m, const float* __restrict__ dis,
    const float* __restrict__ b, const float* __restrict__ Wout,
    const int* __restrict__ batch,
    const int* __restrict__ row_ptr, const int* __restrict__ csr,
    float* gsum, int N, int nwaves){
  int lane = threadIdx.x & 63;
  int sub = lane >> 3, q2 = lane & 7;
  int n = (blockIdx.x*blockDim.x + threadIdx.x) >> 6;
  if (n >= N) return;
  int rp0 = row_ptr[n], rp1 = row_ptr[n+1];
  const float4* b4 = (const float4*)b;
  const float4* wo4 = (const float4*)Wout;
  while (true){
    int nn = n + nwaves;
    int np0 = 0, np1 = 0;
    if (nn < N){ np0 = row_ptr[nn]; np1 = row_ptr[nn+1]; }   // prefetch (indep)
    h8v sf = m[(size_t)n*8 + q2];                            // self row (indep)
    float dn = dis[n];
    int bg = batch[n];
    float acc0=0.f,acc1=0.f,acc2=0.f,acc3=0.f,acc4=0.f,acc5=0.f,acc6=0.f,acc7=0.f;
    int s1 = rp1;
    int j0 = rp0 + sub, j1 = rp0 + 8 + sub;
    if (j0 < s1){ h8v a = m[(size_t)csr[j0]*8 + q2]; ACC8(a); }
    if (j1 < s1){ h8v a = m[(size_t)csr[j1]*8 + q2]; ACC8(a); }
    for (int j = rp0 + 16 + sub; j < s1; j += 8){            // rare (deg>16)
      h8v a = m[(size_t)csr[j]*8 + q2]; ACC8(a);
    }
    RED3(acc0); RED3(acc1); RED3(acc2); RED3(acc3);
    RED3(acc4); RED3(acc5); RED3(acc6); RED3(acc7);
    float2 s01 = __half22float2(sf.a), s23 = __half22float2(sf.b);
    float2 s45 = __half22float2(sf.c), s67 = __half22float2(sf.d);
    float4 bb0 = b4[q2*2], bb1 = b4[q2*2+1];
    float4 w0 = wo4[q2*2], w1 = wo4[q2*2+1];
    float r0 = fmaxf(fmaf(acc0 + s01.x, dn, bb0.x), 0.f);
    float r1 = fmaxf(fmaf(acc1 + s01.y, dn, bb0.y), 0.f);
    float r2 = fmaxf(fmaf(acc2 + s23.x, dn, bb0.z), 0.f);
    float r3 = fmaxf(fmaf(acc3 + s23.y, dn, bb0.w), 0.f);
    float r4 = fmaxf(fmaf(acc4 + s45.x, dn, bb1.x), 0.f);
    float r5 = fmaxf(fmaf(acc5 + s45.y, dn, bb1.y), 0.f);
    float r6 = fmaxf(fmaf(acc6 + s67.x, dn, bb1.z), 0.f);
    float r7 = fmaxf(fmaf(acc7 + s67.y, dn, bb1.w), 0.f);
    float p = r0*w0.x + r1*w0.y + r2*w0.z + r3*w0.w
            + r4*w1.x + r5*w1.y + r6*w1.z + r7*w1.w;
    p += __shfl_xor(p,1,64); p += __shfl_xor(p,2,64); p += __shfl_xor(p,4,64);
    if (lane == 0) atomicAdd(&gsum[bg], p);
    if (nn >= N) break;
    n = nn; rp0 = np0; rp1 = np1;
  }
}

// final: per-graph count via binary search on SORTED batch (no atomics),
// then mean + bias.
__global__ void k_final(const float* __restrict__ gsum, const int* __restrict__ batch,
                        const float* __restrict__ bout, float* __restrict__ out,
                        int G, int N){
  int g = blockIdx.x*blockDim.x + threadIdx.x;
  if (g >= G) return;
  int lo = 0, hi = N;
  while (lo < hi){ int mid = (lo+hi)>>1; if (batch[mid] <  g) lo = mid+1; else hi = mid; }
  int lb = lo;
  lo = 0; hi = N;
  while (lo < hi){ int mid = (lo+hi)>>1; if (batch[mid] <= g) lo = mid+1; else hi = mid; }
  int c = lo - lb;
  out[g] = gsum[g]/(float)(c > 0 ? c : 1) + bout[0];
}

extern "C" void kernel_launch(void* const* d_in, const int* in_sizes, int n_in,
                              void* d_out, int out_size, void* d_ws, size_t ws_size,
                              hipStream_t stream){
  const float* x    = (const float*)d_in[0];
  const int*   ei   = (const int*)d_in[1];
  const int*   batch= (const int*)d_in[2];
  const float* W1 = (const float*)d_in[3];  const float* b1 = (const float*)d_in[4];
  const float* W2 = (const float*)d_in[5];  const float* b2 = (const float*)d_in[6];
  const float* W3 = (const float*)d_in[7];  const float* b3 = (const float*)d_in[8];
  const float* W4 = (const float*)d_in[9];  const float* b4 = (const float*)d_in[10];
  const float* Wout = (const float*)d_in[11]; const float* bout = (const float*)d_in[12];
  float* out = (float*)d_out;

  const int N = in_sizes[0]/9;
  const int E = in_sizes[1]/2;
  const int G = out_size;
  const int* src = ei;        // edge_index[0]
  const int* dst = ei + E;    // edge_index[1]

  char* ws = (char*)d_ws;
  size_t off = 0;
  auto alloc = [&](size_t bytes){ void* p = ws + off; off = align256(off + bytes); return p; };
  int*   row_ptr  = (int*)  alloc((size_t)(N+1)*4);
  int*   csr      = (int*)  alloc((size_t)E*4);
  float* dis      = (float*)alloc((size_t)N*4);
  const int NBK = (N + 127)/128;        // 782 buckets of 128 dst nodes
  const int NC  = (E + CHUNK-1)/CHUNK;  // 245 sort chunks
  int*   hoffC    = (int*)  alloc((size_t)NC*783*4);   // per-chunk bucket offsets
  int*   btot     = (int*)  alloc((size_t)NBK*4);
  float* gsum     = (float*)alloc((size_t)G*4);
  __half* mA      = (__half*)alloc((size_t)N*64*2);  // fp16 message ping
  __half* mB      = (__half*)alloc((size_t)N*64*2);  // fp16 message pong
  // aliases (lifetimes verified):
  int*   binned   = (int*)mA;              // 4MB <= 12.8MB; dead after k_gather2
  float* xs       = (float*)mB;            // N*12*4=4.8MB; dead after k_agg9
  float* xagg     = xs + (size_t)N*12;     // N*12*4=4.8MB; dead after lin1_fused
                                           // 9.6MB <= 12.8MB (mB) ✓
  // m2 = mA (written by lin1_fused, after binned dead)
  // m3 = mB (written by aggF layer2, after xs/xagg dead)
  // m4 = mA (written by aggF layer3, after m2 dead)

  const int AGG_BLOCKS = 2048;             // persistent: 8 blocks/CU on 256 CUs
  const int AGG_WAVES  = AGG_BLOCKS*4;     // 8192 waves; 16*8192 >= N (batch=16)

  k_sortchunk<<<NC, 256, 0, stream>>>(src, dst, binned, hoffC, E);
  k_bktsum   <<<NBK, 256, 0, stream>>>(hoffC, btot, gsum, NC, NBK, G);
  k_gather2  <<<NBK, 256, 0, stream>>>(binned, hoffC, btot, x,
                                       row_ptr, dis, xs, csr, N, NC, E);

  // layer 1: aggregate (padded float4 rows), fused transform
  k_agg9  <<<(N+255)/256, 256, 0, stream>>>((const float4*)xs, dis, row_ptr, csr,
                                            (float4*)xagg, N);
  k_lin1_fused<<<AGG_BLOCKS, 256, 0, stream>>>(xagg, W1, b1, dis, W2, mA, N, AGG_WAVES);

  // layer 2: aggregate m2 -> h2 (regs) -> m3   (uses b2, W3)
  k_agg_fused<<<AGG_BLOCKS, 256, 0, stream>>>((const h8v*)mA, dis, b2, W3,
                                              row_ptr, csr, mB, N, AGG_WAVES);
  // layer 3: aggregate m3 -> h3 (regs) -> m4   (uses b3, W4)
  k_agg_fused<<<AGG_BLOCKS, 256, 0, stream>>>((const h8v*)mB, dis, b3, W4,
                                              row_ptr, csr, mA, N, AGG_WAVES);
  // layer 4: aggregate m4 -> h4 (regs) -> Wout dot -> pooled sums
  k_agg64_out<<<AGG_BLOCKS, 256, 0, stream>>>((const h8v*)mA, dis, b4, Wout, batch,
                                              row_ptr, csr, gsum, N, AGG_WAVES);

  k_final<<<(G+255)/256, 256, 0, stream>>>(gsum, batch, bout, out, G, N);
}